// Round 7
// baseline (308.187 us; speedup 1.0000x reference)
//
#include <hip/hip_runtime.h>
#include <hip/hip_bf16.h>

typedef unsigned int uint;
typedef unsigned short ushort;

#define N_NODES 60000
#define N_EDGES 600000
#define NREL 7
#define NSEG (N_NODES * 8)   // (node, rel) segments, node-major, rel padded to 8
#define D_IN 64
#define DHID 128
#define LEPS 1e-5f

typedef __attribute__((ext_vector_type(8))) short bf16x8v;   // 8 bf16 = 4 VGPRs
typedef __attribute__((ext_vector_type(4))) float f32x4v;    // MFMA accumulator

#define AS1C(p) ((const __attribute__((address_space(1))) void*)(p))
#define AS3(p)  ((__attribute__((address_space(3))) void*)(p))

__device__ __forceinline__ float bf2f(uint u16) {
    return __uint_as_float(u16 << 16);
}
__device__ __forceinline__ uint f2bf(float f) {
    uint u = __float_as_uint(f);
    uint lsb = (u >> 16) & 1u;
    u += 0x7fffu + lsb;
    return u >> 16;
}
__device__ __forceinline__ uint pack2(float a, float b) {
    return f2bf(a) | (f2bf(b) << 16);
}

// ------- merged weight transpose: blocks 0..63 rel/root, 64..65 emb_W ---------
__global__ __launch_bounds__(256) void k_bt2(const float* __restrict__ relW,
                                             const float* __restrict__ rootW,
                                             const float* __restrict__ embW,
                                             ushort* __restrict__ Bt,    // [2][128][1024]
                                             ushort* __restrict__ Bte) { // [128][64]
    __shared__ float t[64][65];
    const int tid = threadIdx.x;
    if (blockIdx.x < 64) {
        const int l  = blockIdx.x >> 5;
        const int kt = (blockIdx.x >> 1) & 15;   // 64-k tile
        const int jt = blockIdx.x & 1;           // 64-j tile
        #pragma unroll
        for (int i = 0; i < 4; ++i) {
            const int idx = i * 256 + tid;       // 0..1023
            const int kr = idx >> 4;             // 0..63
            const int j4 = idx & 15;
            const int kg = kt * 64 + kr;
            const float* src = (kg < 896)
                ? (relW + (size_t)l * 896 * 128 + (size_t)kg * 128)
                : (rootW + (size_t)l * 128 * 128 + (size_t)(kg - 896) * 128);
            const float4 v = *(const float4*)(src + jt * 64 + j4 * 4);
            t[kr][j4 * 4 + 0] = v.x; t[kr][j4 * 4 + 1] = v.y;
            t[kr][j4 * 4 + 2] = v.z; t[kr][j4 * 4 + 3] = v.w;
        }
        __syncthreads();
        uint* btd = (uint*)Bt;
        #pragma unroll
        for (int i = 0; i < 8; ++i) {
            const int idx = i * 256 + tid;       // 0..2047
            const int jr = idx >> 5;             // 0..63
            const int kd = idx & 31;             // dword within 64-k tile
            const uint w = pack2(t[kd * 2][jr], t[kd * 2 + 1][jr]);
            btd[(size_t)l * 65536 + (size_t)(jt * 64 + jr) * 512 + kt * 32 + kd] = w;
        }
    } else {
        const int jt = blockIdx.x - 64;          // 0..1
        #pragma unroll
        for (int i = 0; i < 4; ++i) {
            const int idx = i * 256 + tid;
            const int kr = idx >> 4;             // 0..63
            const int j4 = idx & 15;
            const float4 v = *(const float4*)(embW + (size_t)kr * 128 + jt * 64 + j4 * 4);
            t[kr][j4 * 4 + 0] = v.x; t[kr][j4 * 4 + 1] = v.y;
            t[kr][j4 * 4 + 2] = v.z; t[kr][j4 * 4 + 3] = v.w;
        }
        __syncthreads();
        uint* btd = (uint*)Bte;
        #pragma unroll
        for (int i = 0; i < 8; ++i) {
            const int idx = i * 256 + tid;
            const int jr = idx >> 5;             // 0..63
            const int kd = idx & 31;
            const uint w = pack2(t[kd * 2][jr], t[kd * 2 + 1][jr]);
            btd[(size_t)(jt * 64 + jr) * 32 + kd] = w;
        }
    }
}

// ---------------- MFMA embed: h0 = clip(x,-10,10)@emb_W + emb_b (bf16) ---------
__global__ __launch_bounds__(256) void k_emb(const float* __restrict__ x,
                                             const ushort* __restrict__ Bte, // [128][64]
                                             const float* __restrict__ bias,
                                             ushort* __restrict__ h, int nrows) {
    __shared__ alignas(16) ushort sa[64 * 64];    // 8 KB, swizzled granules
    __shared__ alignas(16) ushort sb[128 * 64];   // 16 KB
    const int tid = threadIdx.x;
    const int lane = tid & 63;
    const int wid = tid >> 6;
    const int wrow = wid >> 1, wcol = wid & 1;
    const int l15 = lane & 15, lh = lane >> 4;
    const int row0 = blockIdx.x * 64;

    #pragma unroll
    for (int i = 0; i < 2; ++i) {
        const int p = i * 256 + tid;
        const int row = p >> 3, gq = p & 7;
        const int n = min(row0 + row, nrows - 1);
        const float4 xa = *(const float4*)(x + (size_t)n * 64 + gq * 8);
        const float4 xb = *(const float4*)(x + (size_t)n * 64 + gq * 8 + 4);
        uint w[4];
        w[0] = pack2(fminf(fmaxf(xa.x, -10.f), 10.f), fminf(fmaxf(xa.y, -10.f), 10.f));
        w[1] = pack2(fminf(fmaxf(xa.z, -10.f), 10.f), fminf(fmaxf(xa.w, -10.f), 10.f));
        w[2] = pack2(fminf(fmaxf(xb.x, -10.f), 10.f), fminf(fmaxf(xb.y, -10.f), 10.f));
        w[3] = pack2(fminf(fmaxf(xb.z, -10.f), 10.f), fminf(fmaxf(xb.w, -10.f), 10.f));
        *(uint4*)&sa[(row * 8 + (gq ^ (row & 7))) * 8] = make_uint4(w[0], w[1], w[2], w[3]);
    }
    #pragma unroll
    for (int i = 0; i < 4; ++i) {
        const int p = i * 256 + tid;
        const int row = p >> 3, gq = p & 7;
        const uint4 v = *(const uint4*)((const uint*)Bte + (size_t)row * 32 + gq * 4);
        *(uint4*)&sb[(row * 8 + (gq ^ (row & 7))) * 8] = v;
    }
    float bv[4];
    #pragma unroll
    for (int fn = 0; fn < 4; ++fn) bv[fn] = bias[wcol * 64 + fn * 16 + l15];
    __syncthreads();

    f32x4v acc[2][4];
    #pragma unroll
    for (int fm = 0; fm < 2; ++fm)
        #pragma unroll
        for (int fn = 0; fn < 4; ++fn)
            acc[fm][fn] = (f32x4v){0.f, 0.f, 0.f, 0.f};
    #pragma unroll
    for (int kh = 0; kh < 2; ++kh) {
        bf16x8v af[2], bfr[4];
        #pragma unroll
        for (int fm = 0; fm < 2; ++fm) {
            const int rowa = wrow * 32 + fm * 16 + l15;
            const int slot = (kh * 4 + lh) ^ (rowa & 7);
            af[fm] = *(const bf16x8v*)&sa[rowa * 64 + slot * 8];
        }
        #pragma unroll
        for (int fn = 0; fn < 4; ++fn) {
            const int rowb = wcol * 64 + fn * 16 + l15;
            const int slot = (kh * 4 + lh) ^ (rowb & 7);
            bfr[fn] = *(const bf16x8v*)&sb[rowb * 64 + slot * 8];
        }
        #pragma unroll
        for (int fm = 0; fm < 2; ++fm)
            #pragma unroll
            for (int fn = 0; fn < 4; ++fn)
                acc[fm][fn] = __builtin_amdgcn_mfma_f32_16x16x32_bf16(
                    af[fm], bfr[fn], acc[fm][fn], 0, 0, 0);
    }
    #pragma unroll
    for (int fm = 0; fm < 2; ++fm)
        #pragma unroll
        for (int r = 0; r < 4; ++r) {
            const int row = row0 + wrow * 32 + fm * 16 + lh * 4 + r;
            if (row < nrows) {
                #pragma unroll
                for (int fn = 0; fn < 4; ++fn) {
                    const int col = wcol * 64 + fn * 16 + l15;
                    h[(size_t)row * 128 + col] = (ushort)f2bf(acc[fm][fn][r] + bv[fn]);
                }
            }
        }
}

// ---------------- CSR build over (dst, rel) segments, node-major --------------
__global__ void k_deg(const int* __restrict__ dst, const int* __restrict__ et,
                      int* __restrict__ deg8) {
    for (int e = blockIdx.x * 256 + threadIdx.x; e < N_EDGES; e += gridDim.x * 256)
        atomicAdd(&deg8[dst[e] * 8 + et[e]], 1);
}
__global__ void k_scan1(const int* __restrict__ in, int* __restrict__ out,
                        int* __restrict__ bsum, int n) {
    __shared__ int s[256];
    const int t = threadIdx.x;
    const int i = blockIdx.x * 256 + t;
    const int v = (i < n) ? in[i] : 0;
    s[t] = v;
    __syncthreads();
    for (int o = 1; o < 256; o <<= 1) {
        int uu = (t >= o) ? s[t - o] : 0;
        __syncthreads();
        s[t] += uu;
        __syncthreads();
    }
    if (i < n) out[i] = s[t] - v;   // exclusive within block
    if (t == 255) bsum[blockIdx.x] = s[255];
}
__global__ void k_scanmid(int* __restrict__ bs, int nb) {
    __shared__ int s[256];
    __shared__ int carrys;
    const int t = threadIdx.x;
    if (t == 0) carrys = 0;
    __syncthreads();
    const int nch = (nb + 255) / 256;
    for (int ch = 0; ch < nch; ++ch) {
        const int i = ch * 256 + t;
        const int v = (i < nb) ? bs[i] : 0;
        s[t] = v;
        __syncthreads();
        for (int o = 1; o < 256; o <<= 1) {
            int uu = (t >= o) ? s[t - o] : 0;
            __syncthreads();
            s[t] += uu;
            __syncthreads();
        }
        const int carry = carrys;
        if (i < nb) bs[i] = s[t] - v + carry;
        __syncthreads();
        if (t == 255) carrys = carry + s[255];
        __syncthreads();
    }
}
__global__ void k_scanadd(int* __restrict__ a, const int* __restrict__ bsums, int n) {
    const int i = blockIdx.x * 256 + threadIdx.x;
    if (i < n) a[i] += bsums[blockIdx.x];
}
__global__ void k_scatter(const int* __restrict__ src, const int* __restrict__ dst,
                          const int* __restrict__ et, const int* __restrict__ rp8,
                          int* __restrict__ fill8, uint* __restrict__ csr32) {
    for (int e = blockIdx.x * 256 + threadIdx.x; e < N_EDGES; e += gridDim.x * 256) {
        const int key = dst[e] * 8 + et[e];
        const int p = rp8[key] + atomicAdd(&fill8[key], 1);
        csr32[p] = (uint)src[e] | ((uint)et[e] << 16);
    }
}

// ---- per-edge routed accumulate (rel is wave-uniform scalar -> scalar branch) --
#define ACCR(R, V) do {                                              \
    const float x0_ = bf2f((V) & 0xFFFFu), x1_ = bf2f((V) >> 16);    \
    switch (R) {                                                     \
        case 0: a0[0] += x0_; a1[0] += x1_; break;                   \
        case 1: a0[1] += x0_; a1[1] += x1_; break;                   \
        case 2: a0[2] += x0_; a1[2] += x1_; break;                   \
        case 3: a0[3] += x0_; a1[3] += x1_; break;                   \
        case 4: a0[4] += x0_; a1[4] += x1_; break;                   \
        case 5: a0[5] += x0_; a1[5] += x1_; break;                   \
        default: a0[6] += x0_; a1[6] += x1_; break;                  \
    } } while (0)

// ===== fused layer: phase1 agg (wave/node -> M rows, L2-local) + phase2 MFMA GEMM
// Block = 128 rows. Phase 1: 8 waves x 16 nodes, flat 8-deep-batched edge loop,
// writes this block's M rows (global -> same-XCD L2). __syncthreads drains.
// Phase 2: round-3-proven pipeline: A=[M|h] + B via global_load_lds w/ pre-
// swizzled source, counted vmcnt(4), raw s_barrier; fused LN+ReLU epilogue.
__global__ __launch_bounds__(512) void k_fused(const uint* __restrict__ h32,   // [N][64] dw
                                               const int* __restrict__ rp8,    // [NSEG]
                                               const uint* __restrict__ csr32,
                                               const ushort* __restrict__ Bt,  // [128][1024]
                                               const float* __restrict__ bias,
                                               const float* __restrict__ g,
                                               const float* __restrict__ bb,
                                               uint* __restrict__ M32,         // [N][448] dw
                                               uint* __restrict__ out,         // bf16 dwords
                                               int nrows) {
    __shared__ alignas(16) union {
        struct { ushort a[2][8192]; ushort b[2][8192]; } s;   // 64 KB staging (dbuf)
        float ep[64 * 132];                                   // 33 KB epilogue half
    } u;
    __shared__ float sbi[DHID], sg[DHID], sbb[DHID];

    const int tid = threadIdx.x;
    if (tid < DHID) { sbi[tid] = bias[tid]; sg[tid] = g[tid]; sbb[tid] = bb[tid]; }
    const int lane = tid & 63;
    const int wid = tid >> 6;        // 0..7
    const int wrow = wid >> 1;       // 0..3: 32-row band (phase 2)
    const int wcol = wid & 1;        // 0..1: 64-col band (phase 2)
    const int row0 = blockIdx.x * 128;

    // staging descriptors (phase 2)
    int prow[2], pG[2], arow[2];
    #pragma unroll
    for (int hf = 0; hf < 2; ++hf) {
        const int p = hf * 512 + wid * 64 + lane;
        const int r = p >> 3;
        prow[hf] = r;
        pG[hf] = (p & 7) ^ (r & 7);
        arow[hf] = min(row0 + r, nrows - 1);
    }
    auto stageA = [&](int buf, int kt) {
        #pragma unroll
        for (int hf = 0; hf < 2; ++hf) {
            const ushort* ga = (kt < 14)
                ? ((const ushort*)M32 + (size_t)arow[hf] * 896 + kt * 64 + pG[hf] * 8)
                : ((const ushort*)h32 + (size_t)arow[hf] * 128 + (kt - 14) * 64 + pG[hf] * 8);
            __builtin_amdgcn_global_load_lds(AS1C(ga),
                AS3(&u.s.a[buf][(hf * 512 + wid * 64) * 8]), 16, 0, 0);
        }
    };
    auto stageB = [&](int buf, int kt) {
        #pragma unroll
        for (int hf = 0; hf < 2; ++hf) {
            const ushort* gb = Bt + (size_t)prow[hf] * 1024 + kt * 64 + pG[hf] * 8;
            __builtin_amdgcn_global_load_lds(AS1C(gb),
                AS3(&u.s.b[buf][(hf * 512 + wid * 64) * 8]), 16, 0, 0);
        }
    };

    stageB(0, 0);   // B(0) rides under phase 1 (drained by the phase barrier)

    // ================= phase 1: aggregate this block's 128 rows =================
    {
        #pragma unroll 1
        for (int i = 0; i < 16; ++i) {
            const int n = row0 + wid * 16 + i;
            if (n >= nrows) break;
            const int4 ba = *(const int4*)(rp8 + n * 8);
            const int4 bbn = *(const int4*)(rp8 + n * 8 + 4);
            const int beg = ba.x, end = bbn.w;   // rel-7 pad empty => bbn.w = node end
            float a0[NREL], a1[NREL];
            #pragma unroll
            for (int r = 0; r < NREL; ++r) { a0[r] = 0.f; a1[r] = 0.f; }
            int e = beg;
            #pragma unroll 1
            for (; e + 8 <= end; e += 8) {
                int t[8];
                #pragma unroll
                for (int q = 0; q < 8; ++q)
                    t[q] = __builtin_amdgcn_readfirstlane((int)csr32[e + q]);
                uint v[8];
                #pragma unroll
                for (int q = 0; q < 8; ++q)
                    v[q] = h32[(size_t)(t[q] & 0xFFFF) * 64 + lane];
                #pragma unroll
                for (int q = 0; q < 8; ++q) ACCR(t[q] >> 16, v[q]);
            }
            #pragma unroll 1
            for (; e < end; ++e) {
                const int t0 = __builtin_amdgcn_readfirstlane((int)csr32[e]);
                const uint v0 = h32[(size_t)(t0 & 0xFFFF) * 64 + lane];
                ACCR(t0 >> 16, v0);
            }
            const int cnt[NREL] = {ba.y - ba.x, ba.z - ba.y, ba.w - ba.z,
                                   bbn.x - ba.w, bbn.y - bbn.x, bbn.z - bbn.y,
                                   bbn.w - bbn.z};
            const size_t base = (size_t)n * 448 + lane;
            #pragma unroll
            for (int r = 0; r < NREL; ++r) {
                const float sc = 1.f / (float)max(cnt[r], 1);
                M32[base + r * 64] = pack2(a0[r] * sc, a1[r] * sc);
            }
        }
    }
    __syncthreads();   // drains M stores (+B0) -> M rows L2/LDS-visible to block

    // ================= phase 2: pipelined MFMA GEMM =================
    f32x4v acc[2][4];
    #pragma unroll
    for (int fm = 0; fm < 2; ++fm)
        #pragma unroll
        for (int fn = 0; fn < 4; ++fn)
            acc[fm][fn] = (f32x4v){0.f, 0.f, 0.f, 0.f};

    auto compute = [&](int buf) {
        #pragma unroll
        for (int kh = 0; kh < 2; ++kh) {
            bf16x8v af[2], bfr[4];
            #pragma unroll
            for (int fm = 0; fm < 2; ++fm) {
                const int rowa = wrow * 32 + fm * 16 + (lane & 15);
                const int sa = (kh * 4 + (lane >> 4)) ^ (rowa & 7);
                af[fm] = *(const bf16x8v*)&u.s.a[buf][rowa * 64 + sa * 8];
            }
            #pragma unroll
            for (int fn = 0; fn < 4; ++fn) {
                const int rowb = wcol * 64 + fn * 16 + (lane & 15);
                const int sb = (kh * 4 + (lane >> 4)) ^ (rowb & 7);
                bfr[fn] = *(const bf16x8v*)&u.s.b[buf][rowb * 64 + sb * 8];
            }
            #pragma unroll
            for (int fm = 0; fm < 2; ++fm)
                #pragma unroll
                for (int fn = 0; fn < 4; ++fn)
                    acc[fm][fn] = __builtin_amdgcn_mfma_f32_16x16x32_bf16(
                        af[fm], bfr[fn], acc[fm][fn], 0, 0, 0);
        }
    };

    stageA(0, 0);                          // outstanding: 2 (B0 drained by barrier)
    #pragma unroll 1
    for (int kt = 0; kt < 16; ++kt) {
        const int cur = kt & 1;
        if (kt < 15) {
            stageA(cur ^ 1, kt + 1);       // +2
            stageB(cur ^ 1, kt + 1);       // +2 -> cur(2|4) + next(4)
            asm volatile("s_waitcnt vmcnt(4)\n\ts_barrier" ::: "memory");
        } else {
            asm volatile("s_waitcnt vmcnt(0)\n\ts_barrier" ::: "memory");
        }
        compute(cur);
        asm volatile("s_barrier" ::: "memory");
    }
    __syncthreads();

    // -------- fused LayerNorm + ReLU epilogue, two 64-row halves --------
    const int hw = wrow >> 1;
    #pragma unroll 1
    for (int hh = 0; hh < 2; ++hh) {
        if (hw == hh) {
            #pragma unroll
            for (int fm = 0; fm < 2; ++fm) {
                const int rl = (wrow & 1) * 32 + fm * 16 + (lane >> 4) * 4;
                #pragma unroll
                for (int fn = 0; fn < 4; ++fn) {
                    const int cl = wcol * 64 + fn * 16 + (lane & 15);
                    const float bi = sbi[cl];
                    #pragma unroll
                    for (int r = 0; r < 4; ++r)
                        u.ep[(rl + r) * 132 + cl] = acc[fm][fn][r] + bi;
                }
            }
        }
        __syncthreads();
        {
            const int r_loc = tid >> 3, cb = tid & 7;   // 8 threads per row
            const int row_g = row0 + hh * 64 + r_loc;
            float v[16];
            float s = 0.f, sq = 0.f;
            #pragma unroll
            for (int q = 0; q < 4; ++q) {
                const float4 t4 = *(const float4*)&u.ep[r_loc * 132 + cb * 16 + q * 4];
                v[4 * q + 0] = t4.x; v[4 * q + 1] = t4.y;
                v[4 * q + 2] = t4.z; v[4 * q + 3] = t4.w;
                s += t4.x + t4.y + t4.z + t4.w;
                sq += t4.x * t4.x + t4.y * t4.y + t4.z * t4.z + t4.w * t4.w;
            }
            s += __shfl_xor(s, 1, 64); sq += __shfl_xor(sq, 1, 64);
            s += __shfl_xor(s, 2, 64); sq += __shfl_xor(sq, 2, 64);
            s += __shfl_xor(s, 4, 64); sq += __shfl_xor(sq, 4, 64);
            const float mean = s * (1.f / 128.f);
            const float var = sq * (1.f / 128.f) - mean * mean;
            const float rs = rsqrtf(var + LEPS);
            if (row_g < nrows) {
                uint o[8];
                #pragma unroll
                for (int q2 = 0; q2 < 8; ++q2) {
                    const int c0 = cb * 16 + 2 * q2;
                    const float va = fmaxf((v[2 * q2]     - mean) * rs * sg[c0]     + sbb[c0],     0.f);
                    const float vb = fmaxf((v[2 * q2 + 1] - mean) * rs * sg[c0 + 1] + sbb[c0 + 1], 0.f);
                    o[q2] = pack2(va, vb);
                }
                uint* op = out + (size_t)row_g * 64 + cb * 8;
                *(uint4*)(op + 0) = make_uint4(o[0], o[1], o[2], o[3]);
                *(uint4*)(op + 4) = make_uint4(o[4], o[5], o[6], o[7]);
            }
        }
        __syncthreads();
    }
}

// ---------------- classifier: MFMA h@W1 + in-register LN/ReLU/W2-dot ----------
__global__ __launch_bounds__(256) void k_cls(const ushort* __restrict__ h16,
                                             const float* __restrict__ W1,   // [128][64]
                                             const float* __restrict__ b1,
                                             const float* __restrict__ lg,
                                             const float* __restrict__ lb,
                                             const float* __restrict__ W2,   // [64]
                                             const float* __restrict__ b2,
                                             float* __restrict__ outp, int nrows) {
    __shared__ ushort Bs[16 * 64 * 8];   // [k-granule g][col j'][8 bf16], 16 KB
    const int tid = threadIdx.x;
    #pragma unroll
    for (int i = 0; i < 8; ++i) {
        const int q = i * 256 + tid;     // 2048 float4 = 8192 f32
        const int k = q >> 4;            // 0..127
        const int j0 = (q & 15) * 4;
        const float4 w = *(const float4*)(W1 + (size_t)k * 64 + j0);
        const int gg = k >> 3, kp = k & 7;
        const int jx = (gg & 3) << 4;
        Bs[(gg * 64 + ((j0 + 0) ^ jx)) * 8 + kp] = (ushort)f2bf(w.x);
        Bs[(gg * 64 + ((j0 + 1) ^ jx)) * 8 + kp] = (ushort)f2bf(w.y);
        Bs[(gg * 64 + ((j0 + 2) ^ jx)) * 8 + kp] = (ushort)f2bf(w.z);
        Bs[(gg * 64 + ((j0 + 3) ^ jx)) * 8 + kp] = (ushort)f2bf(w.w);
    }
    const int lane = tid & 63, wid = tid >> 6;
    const int l15 = lane & 15, lh = lane >> 4;
    float lgv[4], lbv[4], w2v[4], b1v[4];
    #pragma unroll
    for (int fn = 0; fn < 4; ++fn) {
        const int col = fn * 16 + l15;
        lgv[fn] = lg[col]; lbv[fn] = lb[col]; w2v[fn] = W2[col]; b1v[fn] = b1[col];
    }
    const float b2v = b2[0];
    __syncthreads();

    const int row0 = blockIdx.x * 128;
    f32x4v acc[2][4];
    #pragma unroll
    for (int fm = 0; fm < 2; ++fm)
        #pragma unroll
        for (int fn = 0; fn < 4; ++fn)
            acc[fm][fn] = (f32x4v){0.f, 0.f, 0.f, 0.f};

    #pragma unroll
    for (int kk = 0; kk < 4; ++kk) {
        bf16x8v af[2], bfr[4];
        #pragma unroll
        for (int fm = 0; fm < 2; ++fm) {
            const int row = min(row0 + wid * 32 + fm * 16 + l15, nrows - 1);
            af[fm] = *(const bf16x8v*)(h16 + (size_t)row * 128 + kk * 32 + lh * 8);
        }
        #pragma unroll
        for (int fn = 0; fn < 4; ++fn) {
            const int gg = kk * 4 + lh;
            const int jc = fn * 16 + l15;
            bfr[fn] = *(const bf16x8v*)&Bs[(gg * 64 + (jc ^ ((gg & 3) << 4))) * 8];
        }
        #pragma unroll
        for (int fm = 0; fm < 2; ++fm)
            #pragma unroll
            for (int fn = 0; fn < 4; ++fn)
                acc[fm][fn] = __builtin_amdgcn_mfma_f32_16x16x32_bf16(
                    af[fm], bfr[fn], acc[fm][fn], 0, 0, 0);
    }

    #pragma unroll
    for (int fm = 0; fm < 2; ++fm)
        #pragma unroll
        for (int r = 0; r < 4; ++r) {
            float cv[4];
            float s = 0.f, sq = 0.f;
            #pragma unroll
            for (int fn = 0; fn < 4; ++fn) {
                cv[fn] = acc[fm][fn][r] + b1v[fn];
                s += cv[fn]; sq += cv[fn] * cv[fn];
            }
            s += __shfl_xor(s, 1, 64); sq += __shfl_xor(sq, 1, 64);
            s += __shfl_xor(s, 2, 64); sq += __shfl_xor(sq, 2, 64);
            s += __shfl_xor(s, 4, 64); sq += __shfl_xor(sq, 4, 64);
            s += __shfl_xor(s, 8, 64); sq += __shfl_xor(sq, 8, 64);
            const float mean = s * (1.f / 64.f);
            const float var = sq * (1.f / 64.f) - mean * mean;
            const float rs = rsqrtf(var + LEPS);
            float dot = 0.f;
            #pragma unroll
            for (int fn = 0; fn < 4; ++fn)
                dot += fmaxf((cv[fn] - mean) * rs * lgv[fn] + lbv[fn], 0.f) * w2v[fn];
            dot += __shfl_xor(dot, 1, 64);
            dot += __shfl_xor(dot, 2, 64);
            dot += __shfl_xor(dot, 4, 64);
            dot += __shfl_xor(dot, 8, 64);
            const int row = row0 + wid * 32 + fm * 16 + lh * 4 + r;
            if (l15 == 0 && row < nrows) outp[row] = dot + b2v;
        }
}

extern "C" void kernel_launch(void* const* d_in, const int* in_sizes, int n_in,
                              void* d_out, int out_size, void* d_ws, size_t ws_size,
                              hipStream_t stream) {
    const float* x      = (const float*)d_in[0];
    const int*   eidx   = (const int*)d_in[1];
    const int*   etype  = (const int*)d_in[2];
    const float* emb_W  = (const float*)d_in[3];
    const float* emb_b  = (const float*)d_in[4];
    const float* rel_W  = (const float*)d_in[5];
    const float* root_W = (const float*)d_in[6];
    const float* conv_b = (const float*)d_in[7];
    const float* ln_g   = (const float*)d_in[8];
    const float* ln_b   = (const float*)d_in[9];
    const float* cls_W1 = (const float*)d_in[10];
    const float* cls_b1 = (const float*)d_in[11];
    const float* cls_lg = (const float*)d_in[12];
    const float* cls_lb = (const float*)d_in[13];
    const float* cls_W2 = (const float*)d_in[14];
    const float* cls_b2 = (const float*)d_in[15];

    const int* srcv = eidx;
    const int* dstv = eidx + N_EDGES;

    // workspace layout (~145 MB)
    char* ws = (char*)d_ws;
    size_t off = 0;
    auto alloc = [&](size_t bytes) { void* p = ws + off; off += (bytes + 255) & ~(size_t)255; return p; };
    uint*   h0    = (uint*)alloc((size_t)N_NODES * 64 * 4);     // bf16 h, dword-packed
    uint*   h1    = (uint*)alloc((size_t)N_NODES * 64 * 4);
    uint*   M     = (uint*)alloc((size_t)N_NODES * 448 * 4);    // bf16 means (L2-local)
    int*    rp8   = (int*)alloc((size_t)NSEG * 4);
    int*    cnts  = (int*)alloc((size_t)2 * NSEG * 4);          // deg8 | fill8
    uint*   csr32 = (uint*)alloc((size_t)N_EDGES * 4);
    ushort* Btb   = (ushort*)alloc((size_t)2 * 128 * 1024 * 2); // bf16 B^T per layer
    ushort* Bte   = (ushort*)alloc((size_t)128 * 64 * 2);       // bf16 emb_W^T
    int*    bs    = (int*)alloc(8192);
    int*    deg8  = cnts;
    int*    fill8 = cnts + NSEG;
    (void)ws_size; (void)n_in; (void)in_sizes; (void)out_size;

    const int ZB = (NSEG + 255) / 256;             // 1875
    const int FUSED_BLKS = (N_NODES + 127) / 128;  // 469
    const int EMB_BLKS = (N_NODES + 63) / 64;      // 938

    k_bt2<<<66, 256, 0, stream>>>(rel_W, root_W, emb_W, Btb, Bte);
    k_emb<<<EMB_BLKS, 256, 0, stream>>>(x, Bte, emb_b, (ushort*)h0, N_NODES);
    hipMemsetAsync(cnts, 0, (size_t)2 * NSEG * 4, stream);
    k_deg<<<1024, 256, 0, stream>>>(dstv, etype, deg8);
    k_scan1<<<ZB, 256, 0, stream>>>(deg8, rp8, bs, NSEG);
    k_scanmid<<<1, 256, 0, stream>>>(bs, ZB);
    k_scanadd<<<ZB, 256, 0, stream>>>(rp8, bs, NSEG);
    k_scatter<<<1024, 256, 0, stream>>>(srcv, dstv, etype, rp8, fill8, csr32);

    for (int l = 0; l < 2; ++l) {
        const uint* hin = l ? h1 : h0;
        uint* hout = l ? h0 : h1;
        k_fused<<<FUSED_BLKS, 512, 0, stream>>>(
            hin, rp8, csr32,
            Btb + (size_t)l * 131072,
            conv_b + l * 128, ln_g + l * 128, ln_b + l * 128,
            M, hout, N_NODES);
    }
    k_cls<<<469, 256, 0, stream>>>((const ushort*)h0, cls_W1, cls_b1, cls_lg, cls_lb,
                                   cls_W2, cls_b2, (float*)d_out, N_NODES);
}

// Round 8
// 274.552 us; speedup vs baseline: 1.1225x; 1.1225x over previous
//
#include <hip/hip_runtime.h>
#include <hip/hip_bf16.h>

typedef unsigned int uint;
typedef unsigned short ushort;

#define N_NODES 60000
#define N_EDGES 600000
#define NREL 7
#define D_IN 64
#define DHID 128
#define LEPS 1e-5f

typedef __attribute__((ext_vector_type(8))) short bf16x8v;   // 8 bf16 = 4 VGPRs
typedef __attribute__((ext_vector_type(4))) float f32x4v;    // MFMA accumulator

#define AS1C(p) ((const __attribute__((address_space(1))) void*)(p))
#define AS3(p)  ((__attribute__((address_space(3))) void*)(p))

__device__ __forceinline__ float bf2f(uint u16) {
    return __uint_as_float(u16 << 16);
}
__device__ __forceinline__ uint f2bf(float f) {
    uint u = __float_as_uint(f);
    uint lsb = (u >> 16) & 1u;
    u += 0x7fffu + lsb;
    return u >> 16;
}
__device__ __forceinline__ uint pack2(float a, float b) {
    return f2bf(a) | (f2bf(b) << 16);
}

// ------- merged weight transpose: blocks 0..63 rel/root, 64..65 emb_W ---------
__global__ __launch_bounds__(256) void k_bt2(const float* __restrict__ relW,
                                             const float* __restrict__ rootW,
                                             const float* __restrict__ embW,
                                             ushort* __restrict__ Bt,    // [2][128][1024]
                                             ushort* __restrict__ Bte) { // [128][64]
    __shared__ float t[64][65];
    const int tid = threadIdx.x;
    if (blockIdx.x < 64) {
        const int l  = blockIdx.x >> 5;
        const int kt = (blockIdx.x >> 1) & 15;   // 64-k tile
        const int jt = blockIdx.x & 1;           // 64-j tile
        #pragma unroll
        for (int i = 0; i < 4; ++i) {
            const int idx = i * 256 + tid;       // 0..1023
            const int kr = idx >> 4;             // 0..63
            const int j4 = idx & 15;
            const int kg = kt * 64 + kr;
            const float* src = (kg < 896)
                ? (relW + (size_t)l * 896 * 128 + (size_t)kg * 128)
                : (rootW + (size_t)l * 128 * 128 + (size_t)(kg - 896) * 128);
            const float4 v = *(const float4*)(src + jt * 64 + j4 * 4);
            t[kr][j4 * 4 + 0] = v.x; t[kr][j4 * 4 + 1] = v.y;
            t[kr][j4 * 4 + 2] = v.z; t[kr][j4 * 4 + 3] = v.w;
        }
        __syncthreads();
        uint* btd = (uint*)Bt;
        #pragma unroll
        for (int i = 0; i < 8; ++i) {
            const int idx = i * 256 + tid;       // 0..2047
            const int jr = idx >> 5;             // 0..63
            const int kd = idx & 31;             // dword within 64-k tile
            const uint w = pack2(t[kd * 2][jr], t[kd * 2 + 1][jr]);
            btd[(size_t)l * 65536 + (size_t)(jt * 64 + jr) * 512 + kt * 32 + kd] = w;
        }
    } else {
        const int jt = blockIdx.x - 64;          // 0..1
        #pragma unroll
        for (int i = 0; i < 4; ++i) {
            const int idx = i * 256 + tid;
            const int kr = idx >> 4;             // 0..63
            const int j4 = idx & 15;
            const float4 v = *(const float4*)(embW + (size_t)kr * 128 + jt * 64 + j4 * 4);
            t[kr][j4 * 4 + 0] = v.x; t[kr][j4 * 4 + 1] = v.y;
            t[kr][j4 * 4 + 2] = v.z; t[kr][j4 * 4 + 3] = v.w;
        }
        __syncthreads();
        uint* btd = (uint*)Bte;
        #pragma unroll
        for (int i = 0; i < 8; ++i) {
            const int idx = i * 256 + tid;
            const int jr = idx >> 5;             // 0..63
            const int kd = idx & 31;
            const uint w = pack2(t[kd * 2][jr], t[kd * 2 + 1][jr]);
            btd[(size_t)(jt * 64 + jr) * 32 + kd] = w;
        }
    }
}

// ---------------- MFMA embed: h0 = clip(x,-10,10)@emb_W + emb_b (bf16) ---------
__global__ __launch_bounds__(256) void k_emb(const float* __restrict__ x,
                                             const ushort* __restrict__ Bte, // [128][64]
                                             const float* __restrict__ bias,
                                             ushort* __restrict__ h, int nrows) {
    __shared__ alignas(16) ushort sa[64 * 64];    // 8 KB, swizzled granules
    __shared__ alignas(16) ushort sb[128 * 64];   // 16 KB
    const int tid = threadIdx.x;
    const int lane = tid & 63;
    const int wid = tid >> 6;
    const int wrow = wid >> 1, wcol = wid & 1;
    const int l15 = lane & 15, lh = lane >> 4;
    const int row0 = blockIdx.x * 64;

    #pragma unroll
    for (int i = 0; i < 2; ++i) {
        const int p = i * 256 + tid;
        const int row = p >> 3, gq = p & 7;
        const int n = min(row0 + row, nrows - 1);
        const float4 xa = *(const float4*)(x + (size_t)n * 64 + gq * 8);
        const float4 xb = *(const float4*)(x + (size_t)n * 64 + gq * 8 + 4);
        uint w[4];
        w[0] = pack2(fminf(fmaxf(xa.x, -10.f), 10.f), fminf(fmaxf(xa.y, -10.f), 10.f));
        w[1] = pack2(fminf(fmaxf(xa.z, -10.f), 10.f), fminf(fmaxf(xa.w, -10.f), 10.f));
        w[2] = pack2(fminf(fmaxf(xb.x, -10.f), 10.f), fminf(fmaxf(xb.y, -10.f), 10.f));
        w[3] = pack2(fminf(fmaxf(xb.z, -10.f), 10.f), fminf(fmaxf(xb.w, -10.f), 10.f));
        *(uint4*)&sa[(row * 8 + (gq ^ (row & 7))) * 8] = make_uint4(w[0], w[1], w[2], w[3]);
    }
    #pragma unroll
    for (int i = 0; i < 4; ++i) {
        const int p = i * 256 + tid;
        const int row = p >> 3, gq = p & 7;
        const uint4 v = *(const uint4*)((const uint*)Bte + (size_t)row * 32 + gq * 4);
        *(uint4*)&sb[(row * 8 + (gq ^ (row & 7))) * 8] = v;
    }
    float bv[4];
    #pragma unroll
    for (int fn = 0; fn < 4; ++fn) bv[fn] = bias[wcol * 64 + fn * 16 + l15];
    __syncthreads();

    f32x4v acc[2][4];
    #pragma unroll
    for (int fm = 0; fm < 2; ++fm)
        #pragma unroll
        for (int fn = 0; fn < 4; ++fn)
            acc[fm][fn] = (f32x4v){0.f, 0.f, 0.f, 0.f};
    #pragma unroll
    for (int kh = 0; kh < 2; ++kh) {
        bf16x8v af[2], bfr[4];
        #pragma unroll
        for (int fm = 0; fm < 2; ++fm) {
            const int rowa = wrow * 32 + fm * 16 + l15;
            const int slot = (kh * 4 + lh) ^ (rowa & 7);
            af[fm] = *(const bf16x8v*)&sa[rowa * 64 + slot * 8];
        }
        #pragma unroll
        for (int fn = 0; fn < 4; ++fn) {
            const int rowb = wcol * 64 + fn * 16 + l15;
            const int slot = (kh * 4 + lh) ^ (rowb & 7);
            bfr[fn] = *(const bf16x8v*)&sb[rowb * 64 + slot * 8];
        }
        #pragma unroll
        for (int fm = 0; fm < 2; ++fm)
            #pragma unroll
            for (int fn = 0; fn < 4; ++fn)
                acc[fm][fn] = __builtin_amdgcn_mfma_f32_16x16x32_bf16(
                    af[fm], bfr[fn], acc[fm][fn], 0, 0, 0);
    }
    #pragma unroll
    for (int fm = 0; fm < 2; ++fm)
        #pragma unroll
        for (int r = 0; r < 4; ++r) {
            const int row = row0 + wrow * 32 + fm * 16 + lh * 4 + r;
            if (row < nrows) {
                #pragma unroll
                for (int fn = 0; fn < 4; ++fn) {
                    const int col = wcol * 64 + fn * 16 + l15;
                    h[(size_t)row * 128 + col] = (ushort)f2bf(acc[fm][fn][r] + bv[fn]);
                }
            }
        }
}

// ---------------- CSR build: node-keyed (rel kept in entry bits) --------------
__global__ void k_deg(const int* __restrict__ dst, const int* __restrict__ et,
                      int* __restrict__ degn, int* __restrict__ deg8) {
    for (int e = blockIdx.x * 256 + threadIdx.x; e < N_EDGES; e += gridDim.x * 256) {
        const int d = dst[e];
        atomicAdd(&degn[d], 1);
        atomicAdd(&deg8[d * 8 + et[e]], 1);
    }
}
__global__ void k_scan1(const int* __restrict__ in, int* __restrict__ out,
                        int* __restrict__ bsum, int n) {
    __shared__ int s[256];
    const int t = threadIdx.x;
    const int i = blockIdx.x * 256 + t;
    const int v = (i < n) ? in[i] : 0;
    s[t] = v;
    __syncthreads();
    for (int o = 1; o < 256; o <<= 1) {
        int uu = (t >= o) ? s[t - o] : 0;
        __syncthreads();
        s[t] += uu;
        __syncthreads();
    }
    if (i < n) out[i] = s[t] - v;   // exclusive within block
    if (t == 255) bsum[blockIdx.x] = s[255];
}
__global__ void k_scanmid(int* __restrict__ bs, int nb) {
    __shared__ int s[256];
    __shared__ int carrys;
    const int t = threadIdx.x;
    if (t == 0) carrys = 0;
    __syncthreads();
    const int nch = (nb + 255) / 256;
    for (int ch = 0; ch < nch; ++ch) {
        const int i = ch * 256 + t;
        const int v = (i < nb) ? bs[i] : 0;
        s[t] = v;
        __syncthreads();
        for (int o = 1; o < 256; o <<= 1) {
            int uu = (t >= o) ? s[t - o] : 0;
            __syncthreads();
            s[t] += uu;
            __syncthreads();
        }
        const int carry = carrys;
        if (i < nb) bs[i] = s[t] - v + carry;
        __syncthreads();
        if (t == 255) carrys = carry + s[255];
        __syncthreads();
    }
}
__global__ void k_scanadd(int* __restrict__ a, const int* __restrict__ bsums,
                          int n, int setlast) {
    const int i = blockIdx.x * 256 + threadIdx.x;
    if (i < n) a[i] += bsums[blockIdx.x];
    if (setlast && blockIdx.x == 0 && threadIdx.x == 0) a[n] = N_EDGES;
}
__global__ void k_scatter(const int* __restrict__ src, const int* __restrict__ dst,
                          const int* __restrict__ et, const int* __restrict__ rp,
                          int* __restrict__ fill, uint* __restrict__ csr32) {
    for (int e = blockIdx.x * 256 + threadIdx.x; e < N_EDGES; e += gridDim.x * 256) {
        const int d = dst[e];
        const int p = rp[d] + atomicAdd(&fill[d], 1);
        csr32[p] = (uint)src[e] | ((uint)et[e] << 16);   // rel in bits; order free
    }
}

// ---- per-edge routed accumulate (rel is wave-uniform scalar -> scalar branch) --
#define ACCR(R, V) do {                                              \
    const float x0_ = bf2f((V) & 0xFFFFu), x1_ = bf2f((V) >> 16);    \
    switch (R) {                                                     \
        case 0: a0[0] += x0_; a1[0] += x1_; break;                   \
        case 1: a0[1] += x0_; a1[1] += x1_; break;                   \
        case 2: a0[2] += x0_; a1[2] += x1_; break;                   \
        case 3: a0[3] += x0_; a1[3] += x1_; break;                   \
        case 4: a0[4] += x0_; a1[4] += x1_; break;                   \
        case 5: a0[5] += x0_; a1[5] += x1_; break;                   \
        default: a0[6] += x0_; a1[6] += x1_; break;                  \
    } } while (0)

// ---------------- aggregation v3: wave/node, scalar CSR stream, 16-deep MLP ----
__global__ __launch_bounds__(256) void k_agg(const uint* __restrict__ h32,
                                             const int* __restrict__ rp,
                                             const int* __restrict__ cnt8,
                                             const uint* __restrict__ csr32,
                                             uint* __restrict__ M32) {
    const int wave0 = (blockIdx.x * 256 + threadIdx.x) >> 6;
    const int lane = threadIdx.x & 63;
    const int nwaves = gridDim.x * 4;
    for (int n0 = wave0; n0 < N_NODES; n0 += nwaves) {
        const int n = __builtin_amdgcn_readfirstlane(n0);      // SGPR node id
        const int beg = __builtin_amdgcn_readfirstlane(rp[n]); // SGPR bounds
        const int end = __builtin_amdgcn_readfirstlane(rp[n + 1]);
        float a0[NREL], a1[NREL];
        #pragma unroll
        for (int r = 0; r < NREL; ++r) { a0[r] = 0.f; a1[r] = 0.f; }
        int e = beg;
        #pragma unroll 1
        for (; e + 16 <= end; e += 16) {            // 16 indep gathers in flight
            const int4 c0 = *(const int4*)(csr32 + e);
            const int4 c1 = *(const int4*)(csr32 + e + 4);
            const int4 c2 = *(const int4*)(csr32 + e + 8);
            const int4 c3 = *(const int4*)(csr32 + e + 12);
            int t[16] = {c0.x, c0.y, c0.z, c0.w, c1.x, c1.y, c1.z, c1.w,
                         c2.x, c2.y, c2.z, c2.w, c3.x, c3.y, c3.z, c3.w};
            #pragma unroll
            for (int q = 0; q < 16; ++q) t[q] = __builtin_amdgcn_readfirstlane(t[q]);
            uint v[16];
            #pragma unroll
            for (int q = 0; q < 16; ++q)
                v[q] = h32[(size_t)(t[q] & 0xFFFF) * 64 + lane];
            #pragma unroll
            for (int q = 0; q < 16; ++q) ACCR(t[q] >> 16, v[q]);
        }
        #pragma unroll 1
        for (; e + 4 <= end; e += 4) {
            const int4 c0 = *(const int4*)(csr32 + e);
            int t[4] = {c0.x, c0.y, c0.z, c0.w};
            #pragma unroll
            for (int q = 0; q < 4; ++q) t[q] = __builtin_amdgcn_readfirstlane(t[q]);
            uint v[4];
            #pragma unroll
            for (int q = 0; q < 4; ++q)
                v[q] = h32[(size_t)(t[q] & 0xFFFF) * 64 + lane];
            #pragma unroll
            for (int q = 0; q < 4; ++q) ACCR(t[q] >> 16, v[q]);
        }
        #pragma unroll 1
        for (; e < end; ++e) {
            const int t0 = __builtin_amdgcn_readfirstlane((int)csr32[e]);
            const uint v0 = h32[(size_t)(t0 & 0xFFFF) * 64 + lane];
            ACCR(t0 >> 16, v0);
        }
        const int4 ca = *(const int4*)(cnt8 + n * 8);
        const int4 cb = *(const int4*)(cnt8 + n * 8 + 4);
        const int cnt[NREL] = {ca.x, ca.y, ca.z, ca.w, cb.x, cb.y, cb.z};
        const size_t base = (size_t)n * 448 + lane;
        #pragma unroll
        for (int r = 0; r < NREL; ++r) {
            const float sc = 1.f / (float)max(cnt[r], 1);
            M32[base + r * 64] = pack2(a0[r] * sc, a1[r] * sc);
        }
    }
}

// ---------------- MFMA GEMM + LayerNorm + ReLU (8 waves, gload_lds pipeline) ----
__global__ __launch_bounds__(512) void k_gemm_mfma(const ushort* __restrict__ A1,  // [N][896]
                                                   const ushort* __restrict__ A2,  // [N][128]
                                                   const ushort* __restrict__ Bt,  // [128][1024]
                                                   const float* __restrict__ bias,
                                                   const float* __restrict__ g,
                                                   const float* __restrict__ bb,
                                                   uint* __restrict__ out,         // bf16 dwords
                                                   int nrows) {
    __shared__ alignas(16) union {
        struct { ushort a[2][8192]; ushort b[2][8192]; } s;   // 64 KB staging (dbuf)
        float ep[64 * 132];                                   // 33 KB epilogue half
    } u;
    __shared__ float sbi[DHID], sg[DHID], sbb[DHID];

    const int tid = threadIdx.x;
    if (tid < DHID) { sbi[tid] = bias[tid]; sg[tid] = g[tid]; sbb[tid] = bb[tid]; }
    const int lane = tid & 63;
    const int wid = tid >> 6;        // 0..7
    const int wrow = wid >> 1;       // 0..3: 32-row band
    const int wcol = wid & 1;        // 0..1: 64-col band
    const int row0 = blockIdx.x * 128;

    int prow[2], pG[2], arow[2];
    #pragma unroll
    for (int hf = 0; hf < 2; ++hf) {
        const int p = hf * 512 + wid * 64 + lane;
        const int r = p >> 3;
        prow[hf] = r;
        pG[hf] = (p & 7) ^ (r & 7);
        arow[hf] = min(row0 + r, nrows - 1);
    }

    auto stage = [&](int buf, int kt) {
        #pragma unroll
        for (int hf = 0; hf < 2; ++hf) {
            const ushort* ga = (kt < 14)
                ? (A1 + (size_t)arow[hf] * 896 + kt * 64 + pG[hf] * 8)
                : (A2 + (size_t)arow[hf] * 128 + (kt - 14) * 64 + pG[hf] * 8);
            __builtin_amdgcn_global_load_lds(AS1C(ga),
                AS3(&u.s.a[buf][(hf * 512 + wid * 64) * 8]), 16, 0, 0);
            const ushort* gb = Bt + (size_t)prow[hf] * 1024 + kt * 64 + pG[hf] * 8;
            __builtin_amdgcn_global_load_lds(AS1C(gb),
                AS3(&u.s.b[buf][(hf * 512 + wid * 64) * 8]), 16, 0, 0);
        }
    };

    f32x4v acc[2][4];
    #pragma unroll
    for (int fm = 0; fm < 2; ++fm)
        #pragma unroll
        for (int fn = 0; fn < 4; ++fn)
            acc[fm][fn] = (f32x4v){0.f, 0.f, 0.f, 0.f};

    auto compute = [&](int buf) {
        #pragma unroll
        for (int kh = 0; kh < 2; ++kh) {
            bf16x8v af[2], bfr[4];
            #pragma unroll
            for (int fm = 0; fm < 2; ++fm) {
                const int rowa = wrow * 32 + fm * 16 + (lane & 15);
                const int sa = (kh * 4 + (lane >> 4)) ^ (rowa & 7);
                af[fm] = *(const bf16x8v*)&u.s.a[buf][rowa * 64 + sa * 8];
            }
            #pragma unroll
            for (int fn = 0; fn < 4; ++fn) {
                const int rowb = wcol * 64 + fn * 16 + (lane & 15);
                const int sb = (kh * 4 + (lane >> 4)) ^ (rowb & 7);
                bfr[fn] = *(const bf16x8v*)&u.s.b[buf][rowb * 64 + sb * 8];
            }
            #pragma unroll
            for (int fm = 0; fm < 2; ++fm)
                #pragma unroll
                for (int fn = 0; fn < 4; ++fn)
                    acc[fm][fn] = __builtin_amdgcn_mfma_f32_16x16x32_bf16(
                        af[fm], bfr[fn], acc[fm][fn], 0, 0, 0);
        }
    };

    stage(0, 0);
    #pragma unroll 1
    for (int kt = 0; kt < 16; ++kt) {
        const int cur = kt & 1;
        if (kt < 15) {
            stage(cur ^ 1, kt + 1);
            asm volatile("s_waitcnt vmcnt(4)\n\ts_barrier" ::: "memory");
        } else {
            asm volatile("s_waitcnt vmcnt(0)\n\ts_barrier" ::: "memory");
        }
        compute(cur);
        asm volatile("s_barrier" ::: "memory");
    }
    __syncthreads();

    // -------- fused LayerNorm + ReLU epilogue, two 64-row halves --------
    const int hw = wrow >> 1;
    #pragma unroll 1
    for (int hh = 0; hh < 2; ++hh) {
        if (hw == hh) {
            #pragma unroll
            for (int fm = 0; fm < 2; ++fm) {
                const int rl = (wrow & 1) * 32 + fm * 16 + (lane >> 4) * 4;
                #pragma unroll
                for (int fn = 0; fn < 4; ++fn) {
                    const int cl = wcol * 64 + fn * 16 + (lane & 15);
                    const float bi = sbi[cl];
                    #pragma unroll
                    for (int r = 0; r < 4; ++r)
                        u.ep[(rl + r) * 132 + cl] = acc[fm][fn][r] + bi;
                }
            }
        }
        __syncthreads();
        {
            const int r_loc = tid >> 3, cb = tid & 7;   // 8 threads per row
            const int row_g = row0 + hh * 64 + r_loc;
            float v[16];
            float s = 0.f, sq = 0.f;
            #pragma unroll
            for (int q = 0; q < 4; ++q) {
                const float4 t4 = *(const float4*)&u.ep[r_loc * 132 + cb * 16 + q * 4];
                v[4 * q + 0] = t4.x; v[4 * q + 1] = t4.y;
                v[4 * q + 2] = t4.z; v[4 * q + 3] = t4.w;
                s += t4.x + t4.y + t4.z + t4.w;
                sq += t4.x * t4.x + t4.y * t4.y + t4.z * t4.z + t4.w * t4.w;
            }
            s += __shfl_xor(s, 1, 64); sq += __shfl_xor(sq, 1, 64);
            s += __shfl_xor(s, 2, 64); sq += __shfl_xor(sq, 2, 64);
            s += __shfl_xor(s, 4, 64); sq += __shfl_xor(sq, 4, 64);
            const float mean = s * (1.f / 128.f);
            const float var = sq * (1.f / 128.f) - mean * mean;
            const float rs = rsqrtf(var + LEPS);
            if (row_g < nrows) {
                uint o[8];
                #pragma unroll
                for (int q2 = 0; q2 < 8; ++q2) {
                    const int c0 = cb * 16 + 2 * q2;
                    const float va = fmaxf((v[2 * q2]     - mean) * rs * sg[c0]     + sbb[c0],     0.f);
                    const float vb = fmaxf((v[2 * q2 + 1] - mean) * rs * sg[c0 + 1] + sbb[c0 + 1], 0.f);
                    o[q2] = pack2(va, vb);
                }
                uint* op = out + (size_t)row_g * 64 + cb * 8;
                *(uint4*)(op + 0) = make_uint4(o[0], o[1], o[2], o[3]);
                *(uint4*)(op + 4) = make_uint4(o[4], o[5], o[6], o[7]);
            }
        }
        __syncthreads();
    }
}

// ---------------- classifier: MFMA h@W1 + in-register LN/ReLU/W2-dot ----------
__global__ __launch_bounds__(256) void k_cls(const ushort* __restrict__ h16,
                                             const float* __restrict__ W1,   // [128][64]
                                             const float* __restrict__ b1,
                                             const float* __restrict__ lg,
                                             const float* __restrict__ lb,
                                             const float* __restrict__ W2,   // [64]
                                             const float* __restrict__ b2,
                                             float* __restrict__ outp, int nrows) {
    __shared__ ushort Bs[16 * 64 * 8];   // [k-granule g][col j'][8 bf16], 16 KB
    const int tid = threadIdx.x;
    #pragma unroll
    for (int i = 0; i < 8; ++i) {
        const int q = i * 256 + tid;     // 2048 float4 = 8192 f32
        const int k = q >> 4;            // 0..127
        const int j0 = (q & 15) * 4;
        const float4 w = *(const float4*)(W1 + (size_t)k * 64 + j0);
        const int gg = k >> 3, kp = k & 7;
        const int jx = (gg & 3) << 4;
        Bs[(gg * 64 + ((j0 + 0) ^ jx)) * 8 + kp] = (ushort)f2bf(w.x);
        Bs[(gg * 64 + ((j0 + 1) ^ jx)) * 8 + kp] = (ushort)f2bf(w.y);
        Bs[(gg * 64 + ((j0 + 2) ^ jx)) * 8 + kp] = (ushort)f2bf(w.z);
        Bs[(gg * 64 + ((j0 + 3) ^ jx)) * 8 + kp] = (ushort)f2bf(w.w);
    }
    const int lane = tid & 63, wid = tid >> 6;
    const int l15 = lane & 15, lh = lane >> 4;
    float lgv[4], lbv[4], w2v[4], b1v[4];
    #pragma unroll
    for (int fn = 0; fn < 4; ++fn) {
        const int col = fn * 16 + l15;
        lgv[fn] = lg[col]; lbv[fn] = lb[col]; w2v[fn] = W2[col]; b1v[fn] = b1[col];
    }
    const float b2v = b2[0];
    __syncthreads();

    const int row0 = blockIdx.x * 128;
    f32x4v acc[2][4];
    #pragma unroll
    for (int fm = 0; fm < 2; ++fm)
        #pragma unroll
        for (int fn = 0; fn < 4; ++fn)
            acc[fm][fn] = (f32x4v){0.f, 0.f, 0.f, 0.f};

    #pragma unroll
    for (int kk = 0; kk < 4; ++kk) {
        bf16x8v af[2], bfr[4];
        #pragma unroll
        for (int fm = 0; fm < 2; ++fm) {
            const int row = min(row0 + wid * 32 + fm * 16 + l15, nrows - 1);
            af[fm] = *(const bf16x8v*)(h16 + (size_t)row * 128 + kk * 32 + lh * 8);
        }
        #pragma unroll
        for (int fn = 0; fn < 4; ++fn) {
            const int gg = kk * 4 + lh;
            const int jc = fn * 16 + l15;
            bfr[fn] = *(const bf16x8v*)&Bs[(gg * 64 + (jc ^ ((gg & 3) << 4))) * 8];
        }
        #pragma unroll
        for (int fm = 0; fm < 2; ++fm)
            #pragma unroll
            for (int fn = 0; fn < 4; ++fn)
                acc[fm][fn] = __builtin_amdgcn_mfma_f32_16x16x32_bf16(
                    af[fm], bfr[fn], acc[fm][fn], 0, 0, 0);
    }

    #pragma unroll
    for (int fm = 0; fm < 2; ++fm)
        #pragma unroll
        for (int r = 0; r < 4; ++r) {
            float cv[4];
            float s = 0.f, sq = 0.f;
            #pragma unroll
            for (int fn = 0; fn < 4; ++fn) {
                cv[fn] = acc[fm][fn][r] + b1v[fn];
                s += cv[fn]; sq += cv[fn] * cv[fn];
            }
            s += __shfl_xor(s, 1, 64); sq += __shfl_xor(sq, 1, 64);
            s += __shfl_xor(s, 2, 64); sq += __shfl_xor(sq, 2, 64);
            s += __shfl_xor(s, 4, 64); sq += __shfl_xor(sq, 4, 64);
            s += __shfl_xor(s, 8, 64); sq += __shfl_xor(sq, 8, 64);
            const float mean = s * (1.f / 64.f);
            const float var = sq * (1.f / 64.f) - mean * mean;
            const float rs = rsqrtf(var + LEPS);
            float dot = 0.f;
            #pragma unroll
            for (int fn = 0; fn < 4; ++fn)
                dot += fmaxf((cv[fn] - mean) * rs * lgv[fn] + lbv[fn], 0.f) * w2v[fn];
            dot += __shfl_xor(dot, 1, 64);
            dot += __shfl_xor(dot, 2, 64);
            dot += __shfl_xor(dot, 4, 64);
            dot += __shfl_xor(dot, 8, 64);
            const int row = row0 + wid * 32 + fm * 16 + lh * 4 + r;
            if (l15 == 0 && row < nrows) outp[row] = dot + b2v;
        }
}

extern "C" void kernel_launch(void* const* d_in, const int* in_sizes, int n_in,
                              void* d_out, int out_size, void* d_ws, size_t ws_size,
                              hipStream_t stream) {
    const float* x      = (const float*)d_in[0];
    const int*   eidx   = (const int*)d_in[1];
    const int*   etype  = (const int*)d_in[2];
    const float* emb_W  = (const float*)d_in[3];
    const float* emb_b  = (const float*)d_in[4];
    const float* rel_W  = (const float*)d_in[5];
    const float* root_W = (const float*)d_in[6];
    const float* conv_b = (const float*)d_in[7];
    const float* ln_g   = (const float*)d_in[8];
    const float* ln_b   = (const float*)d_in[9];
    const float* cls_W1 = (const float*)d_in[10];
    const float* cls_b1 = (const float*)d_in[11];
    const float* cls_lg = (const float*)d_in[12];
    const float* cls_lb = (const float*)d_in[13];
    const float* cls_W2 = (const float*)d_in[14];
    const float* cls_b2 = (const float*)d_in[15];

    const int* srcv = eidx;
    const int* dstv = eidx + N_EDGES;

    // workspace layout (~141 MB)
    char* ws = (char*)d_ws;
    size_t off = 0;
    auto alloc = [&](size_t bytes) { void* p = ws + off; off += (bytes + 255) & ~(size_t)255; return p; };
    uint*   h0    = (uint*)alloc((size_t)N_NODES * 64 * 4);     // bf16 h, dword-packed
    uint*   h1    = (uint*)alloc((size_t)N_NODES * 64 * 4);
    uint*   M     = (uint*)alloc((size_t)N_NODES * 448 * 4);    // bf16 means, dword-packed
    int*    rp    = (int*)alloc((size_t)(N_NODES + 1) * 4);
    int*    cnts  = (int*)alloc((size_t)(N_NODES * 10) * 4);    // degn | fill | deg8
    uint*   csr32 = (uint*)alloc((size_t)N_EDGES * 4);
    ushort* Btb   = (ushort*)alloc((size_t)2 * 128 * 1024 * 2); // bf16 B^T per layer
    ushort* Bte   = (ushort*)alloc((size_t)128 * 64 * 2);       // bf16 emb_W^T
    int*    bs    = (int*)alloc(4096);
    int*    degn  = cnts;
    int*    fill  = cnts + N_NODES;
    int*    deg8  = cnts + 2 * N_NODES;
    (void)ws_size; (void)n_in; (void)in_sizes; (void)out_size;

    const int SB = (N_NODES + 255) / 256;         // 235
    const int GEMM_BLKS = (N_NODES + 127) / 128;  // 469
    const int EMB_BLKS = (N_NODES + 63) / 64;     // 938

    k_bt2<<<66, 256, 0, stream>>>(rel_W, root_W, emb_W, Btb, Bte);
    k_emb<<<EMB_BLKS, 256, 0, stream>>>(x, Bte, emb_b, (ushort*)h0, N_NODES);
    hipMemsetAsync(cnts, 0, (size_t)(N_NODES * 10) * 4, stream);
    k_deg<<<1024, 256, 0, stream>>>(dstv, etype, degn, deg8);
    k_scan1<<<SB, 256, 0, stream>>>(degn, rp, bs, N_NODES);
    k_scanmid<<<1, 256, 0, stream>>>(bs, SB);
    k_scanadd<<<SB, 256, 0, stream>>>(rp, bs, N_NODES, 1);
    k_scatter<<<1024, 256, 0, stream>>>(srcv, dstv, etype, rp, fill, csr32);

    for (int l = 0; l < 2; ++l) {
        const uint* hin = l ? h1 : h0;
        uint* hout = l ? h0 : h1;
        k_agg<<<2048, 256, 0, stream>>>(hin, rp, deg8, csr32, M);
        k_gemm_mfma<<<GEMM_BLKS, 512, 0, stream>>>(
            (const ushort*)M, (const ushort*)hin,
            Btb + (size_t)l * 131072,
            conv_b + l * 128, ln_g + l * 128, ln_b + l * 128,
            hout, N_NODES);
    }
    k_cls<<<469, 256, 0, stream>>>((const ushort*)h0, cls_W1, cls_b1, cls_lg, cls_lb,
                                   cls_W2, cls_b2, (float*)d_out, N_NODES);
}

// Round 9
// 235.062 us; speedup vs baseline: 1.3111x; 1.1680x over previous
//
#include <hip/hip_runtime.h>
#include <hip/hip_bf16.h>

typedef unsigned int uint;
typedef unsigned short ushort;

#define N_NODES 60000
#define N_EDGES 600000
#define NREL 7
#define D_IN 64
#define DHID 128
#define LEPS 1e-5f
#define EMB_BLKS 938            // (N_NODES+63)/64

typedef __attribute__((ext_vector_type(8))) short bf16x8v;   // 8 bf16 = 4 VGPRs
typedef __attribute__((ext_vector_type(4))) float f32x4v;    // MFMA accumulator
typedef __attribute__((ext_vector_type(2))) float f32x2v;    // pk-add pair

#define AS1C(p) ((const __attribute__((address_space(1))) void*)(p))
#define AS3(p)  ((__attribute__((address_space(3))) void*)(p))

__device__ __forceinline__ float bf2f(uint u16) {
    return __uint_as_float(u16 << 16);
}
__device__ __forceinline__ uint f2bf(float f) {
    uint u = __float_as_uint(f);
    uint lsb = (u >> 16) & 1u;
    u += 0x7fffu + lsb;
    return u >> 16;
}
__device__ __forceinline__ uint pack2(float a, float b) {
    return f2bf(a) | (f2bf(b) << 16);
}

// ===== prep: blocks 0..63 rel/root transpose, 64..65 emb_W transpose, 66+ deg ==
__global__ __launch_bounds__(256) void k_prep(const float* __restrict__ relW,
                                              const float* __restrict__ rootW,
                                              const float* __restrict__ embW,
                                              const int* __restrict__ dst,
                                              const int* __restrict__ et,
                                              ushort* __restrict__ Bt,    // [2][128][1024]
                                              ushort* __restrict__ Bte,   // [128][64]
                                              int* __restrict__ deg8) {
    __shared__ float t[64][65];
    const int tid = threadIdx.x;
    if (blockIdx.x < 64) {
        const int l  = blockIdx.x >> 5;
        const int kt = (blockIdx.x >> 1) & 15;   // 64-k tile
        const int jt = blockIdx.x & 1;           // 64-j tile
        #pragma unroll
        for (int i = 0; i < 4; ++i) {
            const int idx = i * 256 + tid;       // 0..1023
            const int kr = idx >> 4;             // 0..63
            const int j4 = idx & 15;
            const int kg = kt * 64 + kr;
            const float* src = (kg < 896)
                ? (relW + (size_t)l * 896 * 128 + (size_t)kg * 128)
                : (rootW + (size_t)l * 128 * 128 + (size_t)(kg - 896) * 128);
            const float4 v = *(const float4*)(src + jt * 64 + j4 * 4);
            t[kr][j4 * 4 + 0] = v.x; t[kr][j4 * 4 + 1] = v.y;
            t[kr][j4 * 4 + 2] = v.z; t[kr][j4 * 4 + 3] = v.w;
        }
        __syncthreads();
        uint* btd = (uint*)Bt;
        #pragma unroll
        for (int i = 0; i < 8; ++i) {
            const int idx = i * 256 + tid;       // 0..2047
            const int jr = idx >> 5;             // 0..63
            const int kd = idx & 31;
            const uint w = pack2(t[kd * 2][jr], t[kd * 2 + 1][jr]);
            btd[(size_t)l * 65536 + (size_t)(jt * 64 + jr) * 512 + kt * 32 + kd] = w;
        }
    } else if (blockIdx.x < 66) {
        const int jt = blockIdx.x - 64;          // 0..1
        #pragma unroll
        for (int i = 0; i < 4; ++i) {
            const int idx = i * 256 + tid;
            const int kr = idx >> 4;
            const int j4 = idx & 15;
            const float4 v = *(const float4*)(embW + (size_t)kr * 128 + jt * 64 + j4 * 4);
            t[kr][j4 * 4 + 0] = v.x; t[kr][j4 * 4 + 1] = v.y;
            t[kr][j4 * 4 + 2] = v.z; t[kr][j4 * 4 + 3] = v.w;
        }
        __syncthreads();
        uint* btd = (uint*)Bte;
        #pragma unroll
        for (int i = 0; i < 8; ++i) {
            const int idx = i * 256 + tid;
            const int jr = idx >> 5;
            const int kd = idx & 31;
            const uint w = pack2(t[kd * 2][jr], t[kd * 2 + 1][jr]);
            btd[(size_t)(jt * 64 + jr) * 32 + kd] = w;
        }
    } else {
        for (int e = (blockIdx.x - 66) * 256 + tid; e < N_EDGES; e += 1024 * 256)
            atomicAdd(&deg8[dst[e] * 8 + et[e]], 1);
    }
}

// ===== scan: node degrees derived from deg8 (int4x2 sum), exclusive scan ======
__global__ void k_scan1n(const int* __restrict__ deg8, int* __restrict__ rp,
                         int* __restrict__ bsum, int n) {
    __shared__ int s[256];
    const int t = threadIdx.x;
    const int i = blockIdx.x * 256 + t;
    int v = 0;
    if (i < n) {
        const int4 x = *(const int4*)(deg8 + (size_t)i * 8);
        const int4 y = *(const int4*)(deg8 + (size_t)i * 8 + 4);
        v = x.x + x.y + x.z + x.w + y.x + y.y + y.z + y.w;
    }
    s[t] = v;
    __syncthreads();
    for (int o = 1; o < 256; o <<= 1) {
        int uu = (t >= o) ? s[t - o] : 0;
        __syncthreads();
        s[t] += uu;
        __syncthreads();
    }
    if (i < n) rp[i] = s[t] - v;
    if (t == 255) bsum[blockIdx.x] = s[255];
}
__global__ void k_scanmid(int* __restrict__ bs, int nb) {
    __shared__ int s[256];
    __shared__ int carrys;
    const int t = threadIdx.x;
    if (t == 0) carrys = 0;
    __syncthreads();
    const int nch = (nb + 255) / 256;
    for (int ch = 0; ch < nch; ++ch) {
        const int i = ch * 256 + t;
        const int v = (i < nb) ? bs[i] : 0;
        s[t] = v;
        __syncthreads();
        for (int o = 1; o < 256; o <<= 1) {
            int uu = (t >= o) ? s[t - o] : 0;
            __syncthreads();
            s[t] += uu;
            __syncthreads();
        }
        const int carry = carrys;
        if (i < nb) bs[i] = s[t] - v + carry;
        __syncthreads();
        if (t == 255) carrys = carry + s[255];
        __syncthreads();
    }
}
__global__ void k_scanadd(int* __restrict__ a, const int* __restrict__ bsums,
                          int n, int setlast) {
    const int i = blockIdx.x * 256 + threadIdx.x;
    if (i < n) a[i] += bsums[blockIdx.x];
    if (setlast && blockIdx.x == 0 && threadIdx.x == 0) a[n] = N_EDGES;
}

// ===== scatemb: blocks 0..EMB_BLKS-1 MFMA embed; rest CSR scatter =============
__global__ __launch_bounds__(256) void k_scatemb(const float* __restrict__ x,
                                                 const ushort* __restrict__ Bte,
                                                 const float* __restrict__ ebias,
                                                 ushort* __restrict__ h,
                                                 const int* __restrict__ src,
                                                 const int* __restrict__ dst,
                                                 const int* __restrict__ et,
                                                 const int* __restrict__ rp,
                                                 int* __restrict__ fill,
                                                 uint* __restrict__ csr32) {
    __shared__ alignas(16) ushort sa[64 * 64];    // 8 KB
    __shared__ alignas(16) ushort sb[128 * 64];   // 16 KB
    const int tid = threadIdx.x;
    if (blockIdx.x >= EMB_BLKS) {
        for (int e = (blockIdx.x - EMB_BLKS) * 256 + tid; e < N_EDGES; e += 1024 * 256) {
            const int d = dst[e];
            const int p = rp[d] + atomicAdd(&fill[d], 1);
            csr32[p] = (uint)src[e] | ((uint)et[e] << 16);
        }
        return;
    }
    const int lane = tid & 63;
    const int wid = tid >> 6;
    const int wrow = wid >> 1, wcol = wid & 1;
    const int l15 = lane & 15, lh = lane >> 4;
    const int row0 = blockIdx.x * 64;

    #pragma unroll
    for (int i = 0; i < 2; ++i) {
        const int p = i * 256 + tid;
        const int row = p >> 3, gq = p & 7;
        const int n = min(row0 + row, N_NODES - 1);
        const float4 xa = *(const float4*)(x + (size_t)n * 64 + gq * 8);
        const float4 xb = *(const float4*)(x + (size_t)n * 64 + gq * 8 + 4);
        uint w[4];
        w[0] = pack2(fminf(fmaxf(xa.x, -10.f), 10.f), fminf(fmaxf(xa.y, -10.f), 10.f));
        w[1] = pack2(fminf(fmaxf(xa.z, -10.f), 10.f), fminf(fmaxf(xa.w, -10.f), 10.f));
        w[2] = pack2(fminf(fmaxf(xb.x, -10.f), 10.f), fminf(fmaxf(xb.y, -10.f), 10.f));
        w[3] = pack2(fminf(fmaxf(xb.z, -10.f), 10.f), fminf(fmaxf(xb.w, -10.f), 10.f));
        *(uint4*)&sa[(row * 8 + (gq ^ (row & 7))) * 8] = make_uint4(w[0], w[1], w[2], w[3]);
    }
    #pragma unroll
    for (int i = 0; i < 4; ++i) {
        const int p = i * 256 + tid;
        const int row = p >> 3, gq = p & 7;
        const uint4 v = *(const uint4*)((const uint*)Bte + (size_t)row * 32 + gq * 4);
        *(uint4*)&sb[(row * 8 + (gq ^ (row & 7))) * 8] = v;
    }
    float bv[4];
    #pragma unroll
    for (int fn = 0; fn < 4; ++fn) bv[fn] = ebias[wcol * 64 + fn * 16 + l15];
    __syncthreads();

    f32x4v acc[2][4];
    #pragma unroll
    for (int fm = 0; fm < 2; ++fm)
        #pragma unroll
        for (int fn = 0; fn < 4; ++fn)
            acc[fm][fn] = (f32x4v){0.f, 0.f, 0.f, 0.f};
    #pragma unroll
    for (int kh = 0; kh < 2; ++kh) {
        bf16x8v af[2], bfr[4];
        #pragma unroll
        for (int fm = 0; fm < 2; ++fm) {
            const int rowa = wrow * 32 + fm * 16 + l15;
            const int slot = (kh * 4 + lh) ^ (rowa & 7);
            af[fm] = *(const bf16x8v*)&sa[rowa * 64 + slot * 8];
        }
        #pragma unroll
        for (int fn = 0; fn < 4; ++fn) {
            const int rowb = wcol * 64 + fn * 16 + l15;
            const int slot = (kh * 4 + lh) ^ (rowb & 7);
            bfr[fn] = *(const bf16x8v*)&sb[rowb * 64 + slot * 8];
        }
        #pragma unroll
        for (int fm = 0; fm < 2; ++fm)
            #pragma unroll
            for (int fn = 0; fn < 4; ++fn)
                acc[fm][fn] = __builtin_amdgcn_mfma_f32_16x16x32_bf16(
                    af[fm], bfr[fn], acc[fm][fn], 0, 0, 0);
    }
    #pragma unroll
    for (int fm = 0; fm < 2; ++fm)
        #pragma unroll
        for (int r = 0; r < 4; ++r) {
            const int row = row0 + wrow * 32 + fm * 16 + lh * 4 + r;
            if (row < N_NODES) {
                #pragma unroll
                for (int fn = 0; fn < 4; ++fn) {
                    const int col = wcol * 64 + fn * 16 + l15;
                    h[(size_t)row * 128 + col] = (ushort)f2bf(acc[fm][fn][r] + bv[fn]);
                }
            }
        }
}

// ---- per-edge routed accumulate: 2 bit-ops + 1 packed f32 add ----
#define ACC2(R, V) do {                                              \
    f32x2v x_;                                                       \
    x_.x = __uint_as_float((V) << 16);                               \
    x_.y = __uint_as_float((V) & 0xFFFF0000u);                       \
    switch (R) {                                                     \
        case 0: a[0] += x_; break;                                   \
        case 1: a[1] += x_; break;                                   \
        case 2: a[2] += x_; break;                                   \
        case 3: a[3] += x_; break;                                   \
        case 4: a[4] += x_; break;                                   \
        case 5: a[5] += x_; break;                                   \
        default: a[6] += x_; break;                                  \
    } } while (0)

// ===== aggregation v4: wave/node, masked-8 batches, node-pipelined metadata ====
// M layout: [rel][node][128 bf16] -> GEMM k-tiles read a dense 32 KB region.
__global__ __launch_bounds__(256) void k_agg(const uint* __restrict__ h32,
                                             const int* __restrict__ rp,
                                             const int* __restrict__ cnt8,
                                             const uint* __restrict__ csr32,
                                             uint* __restrict__ M32) {
    const int wave0 = (blockIdx.x * 256 + threadIdx.x) >> 6;
    const int lane = threadIdx.x & 63;
    const int nwaves = gridDim.x * 4;
    if (wave0 >= N_NODES) return;

    int n = wave0;
    // prologue metadata for first node
    int rl = rp[n], rh = rp[n + 1];
    int4 ca = *(const int4*)(cnt8 + (size_t)n * 8);
    int4 cb = *(const int4*)(cnt8 + (size_t)n * 8 + 4);

    while (true) {
        const int n_next = n + nwaves;
        const bool has_next = (n_next < N_NODES);
        // prefetch next node's metadata; latency hides under this node's edges
        int rl_n = 0, rh_n = 0;
        int4 ca_n = {0, 0, 0, 0}, cb_n = {0, 0, 0, 0};
        if (has_next) {
            rl_n = rp[n_next];
            rh_n = rp[n_next + 1];
            ca_n = *(const int4*)(cnt8 + (size_t)n_next * 8);
            cb_n = *(const int4*)(cnt8 + (size_t)n_next * 8 + 4);
        }
        const int beg = __builtin_amdgcn_readfirstlane(rl);
        const int end = __builtin_amdgcn_readfirstlane(rh);
        const int cnt[NREL] = {ca.x, ca.y, ca.z, ca.w, cb.x, cb.y, cb.z};

        f32x2v a[NREL];
        #pragma unroll
        for (int r = 0; r < NREL; ++r) a[r] = (f32x2v){0.f, 0.f};

        #pragma unroll 1
        for (int e = beg; e < end; e += 8) {        // masked 8-deep batch
            const int4 c0 = *(const int4*)(csr32 + e);
            const int4 c1 = *(const int4*)(csr32 + e + 4);
            int t[8] = {c0.x, c0.y, c0.z, c0.w, c1.x, c1.y, c1.z, c1.w};
            #pragma unroll
            for (int q = 0; q < 8; ++q) t[q] = __builtin_amdgcn_readfirstlane(t[q]);
            uint v[8];
            #pragma unroll
            for (int q = 0; q < 8; ++q)
                if (e + q < end) v[q] = h32[(size_t)(t[q] & 0xFFFF) * 64 + lane];
            #pragma unroll
            for (int q = 0; q < 8; ++q)
                if (e + q < end) ACC2(t[q] >> 16, v[q]);
        }

        const size_t baseN = (size_t)n * 64 + lane;
        #pragma unroll
        for (int r = 0; r < NREL; ++r) {
            const float sc = 1.f / (float)max(cnt[r], 1);
            M32[(size_t)r * (N_NODES * 64) + baseN] = pack2(a[r].x * sc, a[r].y * sc);
        }
        if (!has_next) break;
        n = n_next; rl = rl_n; rh = rh_n; ca = ca_n; cb = cb_n;
    }
}

// ===== MFMA GEMM + LayerNorm + ReLU (8 waves, gload_lds pipeline) =============
// A1 = M [7][N][128] bf16; A2 = h [N][128]; B = Bt [128][1024] (j-major).
__global__ __launch_bounds__(512) void k_gemm_mfma(const ushort* __restrict__ A1,
                                                   const ushort* __restrict__ A2,
                                                   const ushort* __restrict__ Bt,
                                                   const float* __restrict__ bias,
                                                   const float* __restrict__ g,
                                                   const float* __restrict__ bb,
                                                   uint* __restrict__ out,
                                                   int nrows) {
    __shared__ alignas(16) union {
        struct { ushort a[2][8192]; ushort b[2][8192]; } s;   // 64 KB staging (dbuf)
        float ep[64 * 132];                                   // 33 KB epilogue half
    } u;
    __shared__ float sbi[DHID], sg[DHID], sbb[DHID];

    const int tid = threadIdx.x;
    if (tid < DHID) { sbi[tid] = bias[tid]; sg[tid] = g[tid]; sbb[tid] = bb[tid]; }
    const int lane = tid & 63;
    const int wid = tid >> 6;        // 0..7
    const int wrow = wid >> 1;       // 0..3: 32-row band
    const int wcol = wid & 1;        // 0..1: 64-col band
    const int row0 = blockIdx.x * 128;

    int prow[2], pG[2], arow[2];
    #pragma unroll
    for (int hf = 0; hf < 2; ++hf) {
        const int p = hf * 512 + wid * 64 + lane;
        const int r = p >> 3;
        prow[hf] = r;
        pG[hf] = (p & 7) ^ (r & 7);
        arow[hf] = min(row0 + r, nrows - 1);
    }

    auto stage = [&](int buf, int kt) {
        #pragma unroll
        for (int hf = 0; hf < 2; ++hf) {
            const ushort* ga = (kt < 14)
                ? (A1 + ((size_t)(kt >> 1) * N_NODES + arow[hf]) * 128 + (kt & 1) * 64 + pG[hf] * 8)
                : (A2 + (size_t)arow[hf] * 128 + (kt - 14) * 64 + pG[hf] * 8);
            __builtin_amdgcn_global_load_lds(AS1C(ga),
                AS3(&u.s.a[buf][(hf * 512 + wid * 64) * 8]), 16, 0, 0);
            const ushort* gb = Bt + (size_t)prow[hf] * 1024 + kt * 64 + pG[hf] * 8;
            __builtin_amdgcn_global_load_lds(AS1C(gb),
                AS3(&u.s.b[buf][(hf * 512 + wid * 64) * 8]), 16, 0, 0);
        }
    };

    f32x4v acc[2][4];
    #pragma unroll
    for (int fm = 0; fm < 2; ++fm)
        #pragma unroll
        for (int fn = 0; fn < 4; ++fn)
            acc[fm][fn] = (f32x4v){0.f, 0.f, 0.f, 0.f};

    auto compute = [&](int buf) {
        #pragma unroll
        for (int kh = 0; kh < 2; ++kh) {
            bf16x8v af[2], bfr[4];
            #pragma unroll
            for (int fm = 0; fm < 2; ++fm) {
                const int rowa = wrow * 32 + fm * 16 + (lane & 15);
                const int sa = (kh * 4 + (lane >> 4)) ^ (rowa & 7);
                af[fm] = *(const bf16x8v*)&u.s.a[buf][rowa * 64 + sa * 8];
            }
            #pragma unroll
            for (int fn = 0; fn < 4; ++fn) {
                const int rowb = wcol * 64 + fn * 16 + (lane & 15);
                const int sb = (kh * 4 + (lane >> 4)) ^ (rowb & 7);
                bfr[fn] = *(const bf16x8v*)&u.s.b[buf][rowb * 64 + sb * 8];
            }
            #pragma unroll
            for (int fm = 0; fm < 2; ++fm)
                #pragma unroll
                for (int fn = 0; fn < 4; ++fn)
                    acc[fm][fn] = __builtin_amdgcn_mfma_f32_16x16x32_bf16(
                        af[fm], bfr[fn], acc[fm][fn], 0, 0, 0);
        }
    };

    stage(0, 0);
    #pragma unroll 1
    for (int kt = 0; kt < 16; ++kt) {
        const int cur = kt & 1;
        if (kt < 15) {
            stage(cur ^ 1, kt + 1);
            asm volatile("s_waitcnt vmcnt(4)\n\ts_barrier" ::: "memory");
        } else {
            asm volatile("s_waitcnt vmcnt(0)\n\ts_barrier" ::: "memory");
        }
        compute(cur);
        asm volatile("s_barrier" ::: "memory");
    }
    __syncthreads();

    // -------- fused LayerNorm + ReLU epilogue, two 64-row halves --------
    const int hw = wrow >> 1;
    #pragma unroll 1
    for (int hh = 0; hh < 2; ++hh) {
        if (hw == hh) {
            #pragma unroll
            for (int fm = 0; fm < 2; ++fm) {
                const int rl = (wrow & 1) * 32 + fm * 16 + (lane >> 4) * 4;
                #pragma unroll
                for (int fn = 0; fn < 4; ++fn) {
                    const int cl = wcol * 64 + fn * 16 + (lane & 15);
                    const float bi = sbi[cl];
                    #pragma unroll
                    for (int r = 0; r < 4; ++r)
                        u.ep[(rl + r) * 132 + cl] = acc[fm][fn][r] + bi;
                }
            }
        }
        __syncthreads();
        {
            const int r_loc = tid >> 3, cb = tid & 7;   // 8 threads per row
            const int row_g = row0 + hh * 64 + r_loc;
            float v[16];
            float s = 0.f, sq = 0.f;
            #pragma unroll
            for (int q = 0; q < 4; ++q) {
                const float4 t4 = *(const float4*)&u.ep[r_loc * 132 + cb * 16 + q * 4];
                v[4 * q + 0] = t4.x; v[4 * q + 1] = t4.y;
                v[4 * q + 2] = t4.z; v[4 * q + 3] = t4.w;
                s += t4.x + t4.y + t4.z + t4.w;
                sq += t4.x * t4.x + t4.y * t4.y + t4.z * t4.z + t4.w * t4.w;
            }
            s += __shfl_xor(s, 1, 64); sq += __shfl_xor(sq, 1, 64);
            s += __shfl_xor(s, 2, 64); sq += __shfl_xor(sq, 2, 64);
            s += __shfl_xor(s, 4, 64); sq += __shfl_xor(sq, 4, 64);
            const float mean = s * (1.f / 128.f);
            const float var = sq * (1.f / 128.f) - mean * mean;
            const float rs = rsqrtf(var + LEPS);
            if (row_g < nrows) {
                uint o[8];
                #pragma unroll
                for (int q2 = 0; q2 < 8; ++q2) {
                    const int c0 = cb * 16 + 2 * q2;
                    const float va = fmaxf((v[2 * q2]     - mean) * rs * sg[c0]     + sbb[c0],     0.f);
                    const float vb = fmaxf((v[2 * q2 + 1] - mean) * rs * sg[c0 + 1] + sbb[c0 + 1], 0.f);
                    o[q2] = pack2(va, vb);
                }
                uint* op = out + (size_t)row_g * 64 + cb * 8;
                *(uint4*)(op + 0) = make_uint4(o[0], o[1], o[2], o[3]);
                *(uint4*)(op + 4) = make_uint4(o[4], o[5], o[6], o[7]);
            }
        }
        __syncthreads();
    }
}

// ===== classifier: MFMA h@W1 + in-register LN/ReLU/W2-dot =====================
__global__ __launch_bounds__(256) void k_cls(const ushort* __restrict__ h16,
                                             const float* __restrict__ W1,
                                             const float* __restrict__ b1,
                                             const float* __restrict__ lg,
                                             const float* __restrict__ lb,
                                             const float* __restrict__ W2,
                                             const float* __restrict__ b2,
                                             float* __restrict__ outp, int nrows) {
    __shared__ ushort Bs[16 * 64 * 8];   // 16 KB
    const int tid = threadIdx.x;
    #pragma unroll
    for (int i = 0; i < 8; ++i) {
        const int q = i * 256 + tid;
        const int k = q >> 4;
        const int j0 = (q & 15) * 4;
        const float4 w = *(const float4*)(W1 + (size_t)k * 64 + j0);
        const int gg = k >> 3, kp = k & 7;
        const int jx = (gg & 3) << 4;
        Bs[(gg * 64 + ((j0 + 0) ^ jx)) * 8 + kp] = (ushort)f2bf(w.x);
        Bs[(gg * 64 + ((j0 + 1) ^ jx)) * 8 + kp] = (ushort)f2bf(w.y);
        Bs[(gg * 64 + ((j0 + 2) ^ jx)) * 8 + kp] = (ushort)f2bf(w.z);
        Bs[(gg * 64 + ((j0 + 3) ^ jx)) * 8 + kp] = (ushort)f2bf(w.w);
    }
    const int lane = tid & 63, wid = tid >> 6;
    const int l15 = lane & 15, lh = lane >> 4;
    float lgv[4], lbv[4], w2v[4], b1v[4];
    #pragma unroll
    for (int fn = 0; fn < 4; ++fn) {
        const int col = fn * 16 + l15;
        lgv[fn] = lg[col]; lbv[fn] = lb[col]; w2v[fn] = W2[col]; b1v[fn] = b1[col];
    }
    const float b2v = b2[0];
    __syncthreads();

    const int row0 = blockIdx.x * 128;
    f32x4v acc[2][4];
    #pragma unroll
    for (int fm = 0; fm < 2; ++fm)
        #pragma unroll
        for (int fn = 0; fn < 4; ++fn)
            acc[fm][fn] = (f32x4v){0.f, 0.f, 0.f, 0.f};

    #pragma unroll
    for (int kk = 0; kk < 4; ++kk) {
        bf16x8v af[2], bfr[4];
        #pragma unroll
        for (int fm = 0; fm < 2; ++fm) {
            const int row = min(row0 + wid * 32 + fm * 16 + l15, nrows - 1);
            af[fm] = *(const bf16x8v*)(h16 + (size_t)row * 128 + kk * 32 + lh * 8);
        }
        #pragma unroll
        for (int fn = 0; fn < 4; ++fn) {
            const int gg = kk * 4 + lh;
            const int jc = fn * 16 + l15;
            bfr[fn] = *(const bf16x8v*)&Bs[(gg * 64 + (jc ^ ((gg & 3) << 4))) * 8];
        }
        #pragma unroll
        for (int fm = 0; fm < 2; ++fm)
            #pragma unroll
            for (int fn = 0; fn < 4; ++fn)
                acc[fm][fn] = __builtin_amdgcn_mfma_f32_16x16x32_bf16(
                    af[fm], bfr[fn], acc[fm][fn], 0, 0, 0);
    }

    #pragma unroll
    for (int fm = 0; fm < 2; ++fm)
        #pragma unroll
        for (int r = 0; r < 4; ++r) {
            float cv[4];
            float s = 0.f, sq = 0.f;
            #pragma unroll
            for (int fn = 0; fn < 4; ++fn) {
                cv[fn] = acc[fm][fn][r] + b1v[fn];
                s += cv[fn]; sq += cv[fn] * cv[fn];
            }
            s += __shfl_xor(s, 1, 64); sq += __shfl_xor(sq, 1, 64);
            s += __shfl_xor(s, 2, 64); sq += __shfl_xor(sq, 2, 64);
            s += __shfl_xor(s, 4, 64); sq += __shfl_xor(sq, 4, 64);
            s += __shfl_xor(s, 8, 64); sq += __shfl_xor(sq, 8, 64);
            const float mean = s * (1.f / 64.f);
            const float var = sq * (1.f / 64.f) - mean * mean;
            const float rs = rsqrtf(var + LEPS);
            float dot = 0.f;
            #pragma unroll
            for (int fn = 0; fn < 4; ++fn)
                dot += fmaxf((cv[fn] - mean) * rs * lgv[fn] + lbv[fn], 0.f) * w2v[fn];
            dot += __shfl_xor(dot, 1, 64);
            dot += __shfl_xor(dot, 2, 64);
            dot += __shfl_xor(dot, 4, 64);
            dot += __shfl_xor(dot, 8, 64);
            const int row = row0 + wid * 32 + fm * 16 + lh * 4 + r;
            if (l15 == 0 && row < nrows) outp[row] = dot + b2v;
        }
}

extern "C" void kernel_launch(void* const* d_in, const int* in_sizes, int n_in,
                              void* d_out, int out_size, void* d_ws, size_t ws_size,
                              hipStream_t stream) {
    const float* x      = (const float*)d_in[0];
    const int*   eidx   = (const int*)d_in[1];
    const int*   etype  = (const int*)d_in[2];
    const float* emb_W  = (const float*)d_in[3];
    const float* emb_b  = (const float*)d_in[4];
    const float* rel_W  = (const float*)d_in[5];
    const float* root_W = (const float*)d_in[6];
    const float* conv_b = (const float*)d_in[7];
    const float* ln_g   = (const float*)d_in[8];
    const float* ln_b   = (const float*)d_in[9];
    const float* cls_W1 = (const float*)d_in[10];
    const float* cls_b1 = (const float*)d_in[11];
    const float* cls_lg = (const float*)d_in[12];
    const float* cls_lb = (const float*)d_in[13];
    const float* cls_W2 = (const float*)d_in[14];
    const float* cls_b2 = (const float*)d_in[15];

    const int* srcv = eidx;
    const int* dstv = eidx + N_EDGES;

    // workspace layout (~141 MB)
    char* ws = (char*)d_ws;
    size_t off = 0;
    auto alloc = [&](size_t bytes) { void* p = ws + off; off += (bytes + 255) & ~(size_t)255; return p; };
    uint*   h0    = (uint*)alloc((size_t)N_NODES * 64 * 4);     // bf16 h, dword-packed
    uint*   h1    = (uint*)alloc((size_t)N_NODES * 64 * 4);
    uint*   M     = (uint*)alloc((size_t)NREL * N_NODES * 64 * 4);  // [r][n][64] dwords
    int*    rp    = (int*)alloc((size_t)(N_NODES + 1) * 4);
    int*    cnts  = (int*)alloc((size_t)(N_NODES * 9) * 4);     // deg8 | fill
    uint*   csr32 = (uint*)alloc((size_t)N_EDGES * 4);
    ushort* Btb   = (ushort*)alloc((size_t)2 * 128 * 1024 * 2); // bf16 B^T per layer
    ushort* Bte   = (ushort*)alloc((size_t)128 * 64 * 2);       // bf16 emb_W^T
    int*    bs    = (int*)alloc(4096);
    int*    deg8  = cnts;
    int*    fill  = cnts + N_NODES * 8;
    (void)ws_size; (void)n_in; (void)in_sizes; (void)out_size;

    const int SB = (N_NODES + 255) / 256;         // 235
    const int GEMM_BLKS = (N_NODES + 127) / 128;  // 469

    hipMemsetAsync(cnts, 0, (size_t)(N_NODES * 9) * 4, stream);
    k_prep<<<66 + 1024, 256, 0, stream>>>(rel_W, root_W, emb_W, dstv, etype,
                                          Btb, Bte, deg8);
    k_scan1n<<<SB, 256, 0, stream>>>(deg8, rp, bs, N_NODES);
    k_scanmid<<<1, 256, 0, stream>>>(bs, SB);
    k_scanadd<<<SB, 256, 0, stream>>>(rp, bs, N_NODES, 1);
    k_scatemb<<<EMB_BLKS + 1024, 256, 0, stream>>>(x, Bte, emb_b, (ushort*)h0,
                                                   srcv, dstv, etype, rp, fill, csr32);

    for (int l = 0; l < 2; ++l) {
        const uint* hin = l ? h1 : h0;
        uint* hout = l ? h0 : h1;
        k_agg<<<2048, 256, 0, stream>>>(hin, rp, deg8, csr32, M);
        k_gemm_mfma<<<GEMM_BLKS, 512, 0, stream>>>(
            (const ushort*)M, (const ushort*)hin,
            Btb + (size_t)l * 131072,
            conv_b + l * 128, ln_g + l * 128, ln_b + l * 128,
            hout, N_NODES);
    }
    k_cls<<<469, 256, 0, stream>>>((const ushort*)h0, cls_W1, cls_b1, cls_lg, cls_lb,
                                   cls_W2, cls_b2, (float*)d_out, N_NODES);
}

// Round 10
// 228.197 us; speedup vs baseline: 1.3505x; 1.0301x over previous
//
#include <hip/hip_runtime.h>
#include <hip/hip_bf16.h>

typedef unsigned int uint;
typedef unsigned short ushort;

#define N_NODES 60000
#define N_EDGES 600000
#define NREL 7
#define D_IN 64
#define DHID 128
#define LEPS 1e-5f
#define EMB_BLKS 938            // (N_NODES+63)/64

typedef __attribute__((ext_vector_type(8))) short bf16x8v;   // 8 bf16 = 4 VGPRs
typedef __attribute__((ext_vector_type(4))) float f32x4v;    // MFMA accumulator

#define AS1C(p) ((const __attribute__((address_space(1))) void*)(p))
#define AS3(p)  ((__attribute__((address_space(3))) void*)(p))

__device__ __forceinline__ float bf2f(uint u16) {
    return __uint_as_float(u16 << 16);
}
__device__ __forceinline__ uint f2bf(float f) {
    uint u = __float_as_uint(f);
    uint lsb = (u >> 16) & 1u;
    u += 0x7fffu + lsb;
    return u >> 16;
}
__device__ __forceinline__ uint pack2(float a, float b) {
    return f2bf(a) | (f2bf(b) << 16);
}

// ===== prep: blocks 0..63 W transposes (2l x 8r x 2kt x 2jt 64-tiles),
//       blocks 64..65 emb_W transpose, 66+ deg8 atomics =====================
__global__ __launch_bounds__(256) void k_prep(const float* __restrict__ relW,
                                              const float* __restrict__ rootW,
                                              const float* __restrict__ embW,
                                              const int* __restrict__ dst,
                                              const int* __restrict__ et,
                                              ushort* __restrict__ Btr,   // [2][8][128j][128k]
                                              ushort* __restrict__ Bte,   // [128][64]
                                              int* __restrict__ deg8) {
    __shared__ float t[64][65];
    const int tid = threadIdx.x;
    if (blockIdx.x < 64) {
        const int l  = blockIdx.x >> 5;
        const int b5 = blockIdx.x & 31;
        const int r  = b5 >> 2;              // 0..7 (7 = root)
        const int kt = (b5 >> 1) & 1;
        const int jt = b5 & 1;
        #pragma unroll
        for (int i = 0; i < 4; ++i) {
            const int idx = i * 256 + tid;   // 0..1023
            const int kr = idx >> 4;         // 0..63
            const int j4 = idx & 15;
            const int kg = kt * 64 + kr;
            const float* src = (r < 7)
                ? (relW + (((size_t)l * 7 + r) * 128 + kg) * 128 + jt * 64 + j4 * 4)
                : (rootW + ((size_t)l * 128 + kg) * 128 + jt * 64 + j4 * 4);
            const float4 v = *(const float4*)src;
            t[kr][j4 * 4 + 0] = v.x; t[kr][j4 * 4 + 1] = v.y;
            t[kr][j4 * 4 + 2] = v.z; t[kr][j4 * 4 + 3] = v.w;
        }
        __syncthreads();
        uint* btd = (uint*)Btr;
        #pragma unroll
        for (int i = 0; i < 8; ++i) {
            const int idx = i * 256 + tid;   // 0..2047
            const int jr = idx >> 5;         // 0..63
            const int kd = idx & 31;         // k-dword within 64-k tile
            const uint w = pack2(t[kd * 2][jr], t[kd * 2 + 1][jr]);
            btd[((size_t)(l * 8 + r) * 128 + jt * 64 + jr) * 64 + kt * 32 + kd] = w;
        }
    } else if (blockIdx.x < 66) {
        const int jt = blockIdx.x - 64;      // 0..1
        #pragma unroll
        for (int i = 0; i < 4; ++i) {
            const int idx = i * 256 + tid;
            const int kr = idx >> 4;
            const int j4 = idx & 15;
            const float4 v = *(const float4*)(embW + (size_t)kr * 128 + jt * 64 + j4 * 4);
            t[kr][j4 * 4 + 0] = v.x; t[kr][j4 * 4 + 1] = v.y;
            t[kr][j4 * 4 + 2] = v.z; t[kr][j4 * 4 + 3] = v.w;
        }
        __syncthreads();
        uint* btd = (uint*)Bte;
        #pragma unroll
        for (int i = 0; i < 8; ++i) {
            const int idx = i * 256 + tid;
            const int jr = idx >> 5;
            const int kd = idx & 31;
            const uint w = pack2(t[kd * 2][jr], t[kd * 2 + 1][jr]);
            btd[(size_t)(jt * 64 + jr) * 32 + kd] = w;
        }
    } else {
        for (int e = (blockIdx.x - 66) * 256 + tid; e < N_EDGES; e += 1024 * 256)
            atomicAdd(&deg8[dst[e] * 8 + et[e]], 1);
    }
}

// ===== scan: node degree derived from deg8 row sums, exclusive scan ==========
__global__ void k_scan1n(const int* __restrict__ deg8, int* __restrict__ rp,
                         int* __restrict__ bsum, int n) {
    __shared__ int s[256];
    const int t = threadIdx.x;
    const int i = blockIdx.x * 256 + t;
    int v = 0;
    if (i < n) {
        const int4 x = *(const int4*)(deg8 + (size_t)i * 8);
        const int4 y = *(const int4*)(deg8 + (size_t)i * 8 + 4);
        v = x.x + x.y + x.z + x.w + y.x + y.y + y.z + y.w;
    }
    s[t] = v;
    __syncthreads();
    for (int o = 1; o < 256; o <<= 1) {
        int uu = (t >= o) ? s[t - o] : 0;
        __syncthreads();
        s[t] += uu;
        __syncthreads();
    }
    if (i < n) rp[i] = s[t] - v;
    if (t == 255) bsum[blockIdx.x] = s[255];
}
__global__ void k_scanmid(int* __restrict__ bs, int nb) {
    __shared__ int s[256];
    __shared__ int carrys;
    const int t = threadIdx.x;
    if (t == 0) carrys = 0;
    __syncthreads();
    const int nch = (nb + 255) / 256;
    for (int ch = 0; ch < nch; ++ch) {
        const int i = ch * 256 + t;
        const int v = (i < nb) ? bs[i] : 0;
        s[t] = v;
        __syncthreads();
        for (int o = 1; o < 256; o <<= 1) {
            int uu = (t >= o) ? s[t - o] : 0;
            __syncthreads();
            s[t] += uu;
            __syncthreads();
        }
        const int carry = carrys;
        if (i < nb) bs[i] = s[t] - v + carry;
        __syncthreads();
        if (t == 255) carrys = carry + s[255];
        __syncthreads();
    }
}
__global__ void k_scanadd(int* __restrict__ a, const int* __restrict__ bsums,
                          int n, int setlast) {
    const int i = blockIdx.x * 256 + threadIdx.x;
    if (i < n) a[i] += bsums[blockIdx.x];
    if (setlast && blockIdx.x == 0 && threadIdx.x == 0) a[n] = N_EDGES;
}

// ===== scatemb: blocks < EMB_BLKS MFMA embed; rest scatter (entry + weight) ===
__global__ __launch_bounds__(256) void k_scatemb(const float* __restrict__ x,
                                                 const ushort* __restrict__ Bte,
                                                 const float* __restrict__ ebias,
                                                 ushort* __restrict__ h,
                                                 const int* __restrict__ src,
                                                 const int* __restrict__ dst,
                                                 const int* __restrict__ et,
                                                 const int* __restrict__ rp,
                                                 const int* __restrict__ deg8,
                                                 int* __restrict__ fill,
                                                 uint* __restrict__ csr32,
                                                 float* __restrict__ w32) {
    __shared__ alignas(16) ushort sa[64 * 64];    // 8 KB
    __shared__ alignas(16) ushort sb[128 * 64];   // 16 KB
    const int tid = threadIdx.x;
    if (blockIdx.x >= EMB_BLKS) {
        for (int e = (blockIdx.x - EMB_BLKS) * 256 + tid; e < N_EDGES; e += 1024 * 256) {
            const int d = dst[e];
            const int r = et[e];
            const int p = rp[d] + atomicAdd(&fill[d], 1);
            csr32[p] = (uint)(r * N_NODES + src[e]);        // direct T row index
            w32[p] = 1.0f / (float)deg8[d * 8 + r];         // mean weight
        }
        return;
    }
    const int lane = tid & 63;
    const int wid = tid >> 6;
    const int wrow = wid >> 1, wcol = wid & 1;
    const int l15 = lane & 15, lh = lane >> 4;
    const int row0 = blockIdx.x * 64;

    #pragma unroll
    for (int i = 0; i < 2; ++i) {
        const int p = i * 256 + tid;
        const int row = p >> 3, gq = p & 7;
        const int n = min(row0 + row, N_NODES - 1);
        const float4 xa = *(const float4*)(x + (size_t)n * 64 + gq * 8);
        const float4 xb = *(const float4*)(x + (size_t)n * 64 + gq * 8 + 4);
        uint w[4];
        w[0] = pack2(fminf(fmaxf(xa.x, -10.f), 10.f), fminf(fmaxf(xa.y, -10.f), 10.f));
        w[1] = pack2(fminf(fmaxf(xa.z, -10.f), 10.f), fminf(fmaxf(xa.w, -10.f), 10.f));
        w[2] = pack2(fminf(fmaxf(xb.x, -10.f), 10.f), fminf(fmaxf(xb.y, -10.f), 10.f));
        w[3] = pack2(fminf(fmaxf(xb.z, -10.f), 10.f), fminf(fmaxf(xb.w, -10.f), 10.f));
        *(uint4*)&sa[(row * 8 + (gq ^ (row & 7))) * 8] = make_uint4(w[0], w[1], w[2], w[3]);
    }
    #pragma unroll
    for (int i = 0; i < 4; ++i) {
        const int p = i * 256 + tid;
        const int row = p >> 3, gq = p & 7;
        const uint4 v = *(const uint4*)((const uint*)Bte + (size_t)row * 32 + gq * 4);
        *(uint4*)&sb[(row * 8 + (gq ^ (row & 7))) * 8] = v;
    }
    float bv[4];
    #pragma unroll
    for (int fn = 0; fn < 4; ++fn) bv[fn] = ebias[wcol * 64 + fn * 16 + l15];
    __syncthreads();

    f32x4v acc[2][4];
    #pragma unroll
    for (int fm = 0; fm < 2; ++fm)
        #pragma unroll
        for (int fn = 0; fn < 4; ++fn)
            acc[fm][fn] = (f32x4v){0.f, 0.f, 0.f, 0.f};
    #pragma unroll
    for (int kh = 0; kh < 2; ++kh) {
        bf16x8v af[2], bfr[4];
        #pragma unroll
        for (int fm = 0; fm < 2; ++fm) {
            const int rowa = wrow * 32 + fm * 16 + l15;
            const int slot = (kh * 4 + lh) ^ (rowa & 7);
            af[fm] = *(const bf16x8v*)&sa[rowa * 64 + slot * 8];
        }
        #pragma unroll
        for (int fn = 0; fn < 4; ++fn) {
            const int rowb = wcol * 64 + fn * 16 + l15;
            const int slot = (kh * 4 + lh) ^ (rowb & 7);
            bfr[fn] = *(const bf16x8v*)&sb[rowb * 64 + slot * 8];
        }
        #pragma unroll
        for (int fm = 0; fm < 2; ++fm)
            #pragma unroll
            for (int fn = 0; fn < 4; ++fn)
                acc[fm][fn] = __builtin_amdgcn_mfma_f32_16x16x32_bf16(
                    af[fm], bfr[fn], acc[fm][fn], 0, 0, 0);
    }
    #pragma unroll
    for (int fm = 0; fm < 2; ++fm)
        #pragma unroll
        for (int r = 0; r < 4; ++r) {
            const int row = row0 + wrow * 32 + fm * 16 + lh * 4 + r;
            if (row < N_NODES) {
                #pragma unroll
                for (int fn = 0; fn < 4; ++fn) {
                    const int col = wcol * 64 + fn * 16 + l15;
                    h[(size_t)row * 128 + col] = (ushort)f2bf(acc[fm][fn][r] + bv[fn]);
                }
            }
        }
}

// ===== transform GEMM: T[bj] = h @ W_bj (bj 0..6 rel, 7 root); K=128 ==========
__global__ __launch_bounds__(512) void k_trans(const ushort* __restrict__ h16,  // [N][128]
                                               const ushort* __restrict__ Btr,  // [8][128j][128k]
                                               ushort* __restrict__ T16,        // [8][N][128]
                                               int nrows) {
    __shared__ alignas(16) ushort sa[2][8192];   // 32 KB: A (128 rows x 64 k) x2
    __shared__ alignas(16) ushort sb[2][8192];   // 32 KB: B (128 j x 64 k) x2
    const int tid = threadIdx.x;
    const int lane = tid & 63;
    const int wid = tid >> 6;
    const int wrow = wid >> 1, wcol = wid & 1;
    const int l15 = lane & 15, lh = lane >> 4;
    const int row0 = blockIdx.x * 128;
    const int bj = blockIdx.y;

    int prow[2], pG[2], arow[2];
    #pragma unroll
    for (int hf = 0; hf < 2; ++hf) {
        const int p = hf * 512 + wid * 64 + lane;
        const int r = p >> 3;
        prow[hf] = r;
        pG[hf] = (p & 7) ^ (r & 7);
        arow[hf] = min(row0 + r, nrows - 1);
    }
    #pragma unroll
    for (int kt = 0; kt < 2; ++kt) {
        #pragma unroll
        for (int hf = 0; hf < 2; ++hf) {
            const ushort* ga = h16 + (size_t)arow[hf] * 128 + kt * 64 + pG[hf] * 8;
            __builtin_amdgcn_global_load_lds(AS1C(ga),
                AS3(&sa[kt][(hf * 512 + wid * 64) * 8]), 16, 0, 0);
            const ushort* gb = Btr + ((size_t)bj * 128 + prow[hf]) * 128 + kt * 64 + pG[hf] * 8;
            __builtin_amdgcn_global_load_lds(AS1C(gb),
                AS3(&sb[kt][(hf * 512 + wid * 64) * 8]), 16, 0, 0);
        }
    }
    __syncthreads();

    f32x4v acc[2][4];
    #pragma unroll
    for (int fm = 0; fm < 2; ++fm)
        #pragma unroll
        for (int fn = 0; fn < 4; ++fn)
            acc[fm][fn] = (f32x4v){0.f, 0.f, 0.f, 0.f};

    #pragma unroll
    for (int kt = 0; kt < 2; ++kt)
        #pragma unroll
        for (int kh = 0; kh < 2; ++kh) {
            bf16x8v af[2], bfr[4];
            #pragma unroll
            for (int fm = 0; fm < 2; ++fm) {
                const int rowa = wrow * 32 + fm * 16 + l15;
                const int slot = (kh * 4 + lh) ^ (rowa & 7);
                af[fm] = *(const bf16x8v*)&sa[kt][rowa * 64 + slot * 8];
            }
            #pragma unroll
            for (int fn = 0; fn < 4; ++fn) {
                const int rowb = wcol * 64 + fn * 16 + l15;
                const int slot = (kh * 4 + lh) ^ (rowb & 7);
                bfr[fn] = *(const bf16x8v*)&sb[kt][rowb * 64 + slot * 8];
            }
            #pragma unroll
            for (int fm = 0; fm < 2; ++fm)
                #pragma unroll
                for (int fn = 0; fn < 4; ++fn)
                    acc[fm][fn] = __builtin_amdgcn_mfma_f32_16x16x32_bf16(
                        af[fm], bfr[fn], acc[fm][fn], 0, 0, 0);
        }

    #pragma unroll
    for (int fm = 0; fm < 2; ++fm)
        #pragma unroll
        for (int r = 0; r < 4; ++r) {
            const int row = row0 + wrow * 32 + fm * 16 + lh * 4 + r;
            if (row < nrows) {
                ushort* tp = T16 + ((size_t)bj * N_NODES + row) * 128 + wcol * 64 + l15;
                #pragma unroll
                for (int fn = 0; fn < 4; ++fn)
                    tp[fn * 16] = (ushort)f2bf(acc[fm][fn][r]);
            }
        }
}

// ===== gather: out[n] = LNReLU( sum_e w_e*T[idx_e] + T[root][n] + bias ) ======
__global__ __launch_bounds__(256) void k_gather(const uint* __restrict__ T32,  // [8][N][64] dw
                                                const int* __restrict__ rp,
                                                const uint* __restrict__ csr32,
                                                const float* __restrict__ w32,
                                                const float* __restrict__ bias,
                                                const float* __restrict__ g,
                                                const float* __restrict__ bb,
                                                uint* __restrict__ hout) {
    const int wave = (blockIdx.x * 256 + threadIdx.x) >> 6;
    const int lane = threadIdx.x & 63;
    const int nwaves = gridDim.x * 4;
    const float2 bias2 = *(const float2*)(bias + 2 * lane);
    const float2 g2 = *(const float2*)(g + 2 * lane);
    const float2 b2 = *(const float2*)(bb + 2 * lane);
    #pragma unroll 1
    for (int n0 = wave; n0 < N_NODES; n0 += nwaves) {
        const int n = __builtin_amdgcn_readfirstlane(n0);
        const int beg = __builtin_amdgcn_readfirstlane(rp[n]);
        const int end = __builtin_amdgcn_readfirstlane(rp[n + 1]);
        float ax = 0.f, ay = 0.f;
        #pragma unroll 1
        for (int e = beg; e < end; e += 8) {            // masked 8-deep batch
            const int4 c0 = *(const int4*)(csr32 + e);
            const int4 c1 = *(const int4*)(csr32 + e + 4);
            const float4 w0 = *(const float4*)(w32 + e);
            const float4 w1 = *(const float4*)(w32 + e + 4);
            int t[8] = {c0.x, c0.y, c0.z, c0.w, c1.x, c1.y, c1.z, c1.w};
            const float w[8] = {w0.x, w0.y, w0.z, w0.w, w1.x, w1.y, w1.z, w1.w};
            #pragma unroll
            for (int q = 0; q < 8; ++q) t[q] = __builtin_amdgcn_readfirstlane(t[q]);
            uint v[8];
            #pragma unroll
            for (int q = 0; q < 8; ++q)
                if (e + q < end) v[q] = T32[(size_t)t[q] * 64 + lane];
            #pragma unroll
            for (int q = 0; q < 8; ++q)
                if (e + q < end) {
                    ax += w[q] * __uint_as_float(v[q] << 16);
                    ay += w[q] * __uint_as_float(v[q] & 0xFFFF0000u);
                }
        }
        const uint vr = T32[((size_t)7 * N_NODES + n) * 64 + lane];   // root term
        const float c0f = ax + bf2f(vr & 0xFFFFu) + bias2.x;
        const float c1f = ay + bf2f(vr >> 16) + bias2.y;
        float s = c0f + c1f, sq = c0f * c0f + c1f * c1f;
        #pragma unroll
        for (int o = 1; o < 64; o <<= 1) {
            s += __shfl_xor(s, o, 64);
            sq += __shfl_xor(sq, o, 64);
        }
        const float mean = s * (1.f / 128.f);
        const float var = sq * (1.f / 128.f) - mean * mean;
        const float rs = rsqrtf(var + LEPS);
        const float y0 = fmaxf((c0f - mean) * rs * g2.x + b2.x, 0.f);
        const float y1 = fmaxf((c1f - mean) * rs * g2.y + b2.y, 0.f);
        hout[(size_t)n * 64 + lane] = pack2(y0, y1);
    }
}

// ===== classifier: MFMA h@W1 + in-register LN/ReLU/W2-dot =====================
__global__ __launch_bounds__(256) void k_cls(const ushort* __restrict__ h16,
                                             const float* __restrict__ W1,
                                             const float* __restrict__ b1,
                                             const float* __restrict__ lg,
                                             const float* __restrict__ lb,
                                             const float* __restrict__ W2,
                                             const float* __restrict__ b2,
                                             float* __restrict__ outp, int nrows) {
    __shared__ ushort Bs[16 * 64 * 8];   // 16 KB
    const int tid = threadIdx.x;
    #pragma unroll
    for (int i = 0; i < 8; ++i) {
        const int q = i * 256 + tid;
        const int k = q >> 4;
        const int j0 = (q & 15) * 4;
        const float4 w = *(const float4*)(W1 + (size_t)k * 64 + j0);
        const int gg = k >> 3, kp = k & 7;
        const int jx = (gg & 3) << 4;
        Bs[(gg * 64 + ((j0 + 0) ^ jx)) * 8 + kp] = (ushort)f2bf(w.x);
        Bs[(gg * 64 + ((j0 + 1) ^ jx)) * 8 + kp] = (ushort)f2bf(w.y);
        Bs[(gg * 64 + ((j0 + 2) ^ jx)) * 8 + kp] = (ushort)f2bf(w.z);
        Bs[(gg * 64 + ((j0 + 3) ^ jx)) * 8 + kp] = (ushort)f2bf(w.w);
    }
    const int lane = tid & 63, wid = tid >> 6;
    const int l15 = lane & 15, lh = lane >> 4;
    float lgv[4], lbv[4], w2v[4], b1v[4];
    #pragma unroll
    for (int fn = 0; fn < 4; ++fn) {
        const int col = fn * 16 + l15;
        lgv[fn] = lg[col]; lbv[fn] = lb[col]; w2v[fn] = W2[col]; b1v[fn] = b1[col];
    }
    const float b2v = b2[0];
    __syncthreads();

    const int row0 = blockIdx.x * 128;
    f32x4v acc[2][4];
    #pragma unroll
    for (int fm = 0; fm < 2; ++fm)
        #pragma unroll
        for (int fn = 0; fn < 4; ++fn)
            acc[fm][fn] = (f32x4v){0.f, 0.f, 0.f, 0.f};

    #pragma unroll
    for (int kk = 0; kk < 4; ++kk) {
        bf16x8v af[2], bfr[4];
        #pragma unroll
        for (int fm = 0; fm < 2; ++fm) {
            const int row = min(row0 + wid * 32 + fm * 16 + l15, nrows - 1);
            af[fm] = *(const bf16x8v*)(h16 + (size_t)row * 128 + kk * 32 + lh * 8);
        }
        #pragma unroll
        for (int fn = 0; fn < 4; ++fn) {
            const int gg = kk * 4 + lh;
            const int jc = fn * 16 + l15;
            bfr[fn] = *(const bf16x8v*)&Bs[(gg * 64 + (jc ^ ((gg & 3) << 4))) * 8];
        }
        #pragma unroll
        for (int fm = 0; fm < 2; ++fm)
            #pragma unroll
            for (int fn = 0; fn < 4; ++fn)
                acc[fm][fn] = __builtin_amdgcn_mfma_f32_16x16x32_bf16(
                    af[fm], bfr[fn], acc[fm][fn], 0, 0, 0);
    }

    #pragma unroll
    for (int fm = 0; fm < 2; ++fm)
        #pragma unroll
        for (int r = 0; r < 4; ++r) {
            float cv[4];
            float s = 0.f, sq = 0.f;
            #pragma unroll
            for (int fn = 0; fn < 4; ++fn) {
                cv[fn] = acc[fm][fn][r] + b1v[fn];
                s += cv[fn]; sq += cv[fn] * cv[fn];
            }
            s += __shfl_xor(s, 1, 64); sq += __shfl_xor(sq, 1, 64);
            s += __shfl_xor(s, 2, 64); sq += __shfl_xor(sq, 2, 64);
            s += __shfl_xor(s, 4, 64); sq += __shfl_xor(sq, 4, 64);
            s += __shfl_xor(s, 8, 64); sq += __shfl_xor(sq, 8, 64);
            const float mean = s * (1.f / 64.f);
            const float var = sq * (1.f / 64.f) - mean * mean;
            const float rs = rsqrtf(var + LEPS);
            float dot = 0.f;
            #pragma unroll
            for (int fn = 0; fn < 4; ++fn)
                dot += fmaxf((cv[fn] - mean) * rs * lgv[fn] + lbv[fn], 0.f) * w2v[fn];
            dot += __shfl_xor(dot, 1, 64);
            dot += __shfl_xor(dot, 2, 64);
            dot += __shfl_xor(dot, 4, 64);
            dot += __shfl_xor(dot, 8, 64);
            const int row = row0 + wid * 32 + fm * 16 + lh * 4 + r;
            if (l15 == 0 && row < nrows) outp[row] = dot + b2v;
        }
}

extern "C" void kernel_launch(void* const* d_in, const int* in_sizes, int n_in,
                              void* d_out, int out_size, void* d_ws, size_t ws_size,
                              hipStream_t stream) {
    const float* x      = (const float*)d_in[0];
    const int*   eidx   = (const int*)d_in[1];
    const int*   etype  = (const int*)d_in[2];
    const float* emb_W  = (const float*)d_in[3];
    const float* emb_b  = (const float*)d_in[4];
    const float* rel_W  = (const float*)d_in[5];
    const float* root_W = (const float*)d_in[6];
    const float* conv_b = (const float*)d_in[7];
    const float* ln_g   = (const float*)d_in[8];
    const float* ln_b   = (const float*)d_in[9];
    const float* cls_W1 = (const float*)d_in[10];
    const float* cls_b1 = (const float*)d_in[11];
    const float* cls_lg = (const float*)d_in[12];
    const float* cls_lb = (const float*)d_in[13];
    const float* cls_W2 = (const float*)d_in[14];
    const float* cls_b2 = (const float*)d_in[15];

    const int* srcv = eidx;
    const int* dstv = eidx + N_EDGES;

    // workspace layout (~146 MB): single h buffer (gather never reads h)
    char* ws = (char*)d_ws;
    size_t off = 0;
    auto alloc = [&](size_t bytes) { void* p = ws + off; off += (bytes + 255) & ~(size_t)255; return p; };
    ushort* h     = (ushort*)alloc((size_t)N_NODES * 128 * 2);          // bf16 h
    ushort* T     = (ushort*)alloc((size_t)8 * N_NODES * 128 * 2);      // bf16 T [8][N][128]
    int*    rp    = (int*)alloc((size_t)(N_NODES + 1) * 4);
    int*    cnts  = (int*)alloc((size_t)(N_NODES * 9) * 4);             // deg8 | fill
    uint*   csr32 = (uint*)alloc((size_t)N_EDGES * 4);
    float*  w32   = (float*)alloc((size_t)N_EDGES * 4);
    ushort* Btr   = (ushort*)alloc((size_t)2 * 8 * 128 * 128 * 2);      // bf16 W^T
    ushort* Bte   = (ushort*)alloc((size_t)128 * 64 * 2);               // bf16 emb_W^T
    int*    bs    = (int*)alloc(4096);
    int*    deg8  = cnts;
    int*    fill  = cnts + N_NODES * 8;
    (void)ws_size; (void)n_in; (void)in_sizes; (void)out_size;

    const int SB = (N_NODES + 255) / 256;         // 235
    const int ROW_BLKS = (N_NODES + 127) / 128;   // 469

    hipMemsetAsync(cnts, 0, (size_t)(N_NODES * 9) * 4, stream);
    k_prep<<<66 + 1024, 256, 0, stream>>>(rel_W, root_W, emb_W, dstv, etype,
                                          Btr, Bte, deg8);
    k_scan1n<<<SB, 256, 0, stream>>>(deg8, rp, bs, N_NODES);
    k_scanmid<<<1, 256, 0, stream>>>(bs, SB);
    k_scanadd<<<SB, 256, 0, stream>>>(rp, bs, N_NODES, 1);
    k_scatemb<<<EMB_BLKS + 1024, 256, 0, stream>>>(x, Bte, emb_b, h,
                                                   srcv, dstv, etype, rp, deg8,
                                                   fill, csr32, w32);

    for (int l = 0; l < 2; ++l) {
        k_trans<<<dim3(ROW_BLKS, 8), 512, 0, stream>>>(
            h, Btr + (size_t)l * 131072, T, N_NODES);
        k_gather<<<2048, 256, 0, stream>>>(
            (const uint*)T, rp, csr32, w32,
            conv_b + l * 128, ln_g + l * 128, ln_b + l * 128,
            (uint*)h);
    }
    k_cls<<<469, 256, 0, stream>>>(h, cls_W1, cls_b1, cls_lg, cls_lb,
                                   cls_W2, cls_b2, (float*)d_out, N_NODES);
}